// Round 2
// baseline (371.024 us; speedup 1.0000x reference)
//
#include <hip/hip_runtime.h>
#include <hip/hip_bf16.h>

// B=8, N=2048, D=384, R=64, H=W=256.
// Inputs:  x (B,N,D) f32, segments (B,H,W) i32, prototypes (1,R,D) f32.
// Outputs (f32, concat): out (B,N,D) | segments (B,H,W) | loss (1) | C (B,N,R)
//
// Pipeline (7 dispatches):
//   memset(maskp+prox) ; k_proto ; k_seg ; k_csim (S normalized + colsum
//   partials + bf16 xT) ; k_lossfc (loss partials + C + Kbf) ;
//   k_qkpv (FUSED: per K-tile, P=mask.*(ChatChat^T) -> LDS (dbuf), then
//   out += P X with rowsum via ones-MFMA; P never touches HBM) ;
//   k_segout (+ loss final reduce in block 0).
#define NB 8
#define NN 2048
#define ND 384
#define NR 64
#define OUT_ELEMS (NB*NN*ND)        // 6291456
#define SEG_ELEMS (NB*256*256)      // 524288
#define NBLK_LOSS (NB*NN/4)         // 4096

typedef float  f32x4  __attribute__((ext_vector_type(4)));
typedef short  bf16x8 __attribute__((ext_vector_type(8)));

__device__ inline float wsum(float v){
  #pragma unroll
  for(int o=32;o;o>>=1) v += __shfl_xor(v,o,64);
  return v;
}
__device__ inline float wmax(float v){
  #pragma unroll
  for(int o=32;o;o>>=1) v = fmaxf(v,__shfl_xor(v,o,64));
  return v;
}
__device__ inline unsigned short f2bf(float f){
  unsigned u = __float_as_uint(f);
  return (unsigned short)((u + 0x8000u) >> 16);
}

// ---- normalize prototypes -> kn (f32, unit rows) ----
__global__ void k_proto(const float* __restrict__ protos, float* __restrict__ kn){
  int r = blockIdx.x, l = threadIdx.x;
  float v[6]; float ss = 0.f;
  #pragma unroll
  for(int i=0;i<6;i++){ v[i] = protos[r*ND + l*6 + i]; ss += v[i]*v[i]; }
  ss = wsum(ss);
  float inv = 1.f / fmaxf(sqrtf(ss), 1e-8f);
  #pragma unroll
  for(int i=0;i<6;i++) kn[r*ND + l*6 + i] = v[i]*inv;
}

// ---- segments -> node mask + prox bitmask rows (64 u32/node) ----
__global__ void k_seg(const int* __restrict__ seg, float* __restrict__ mask, unsigned* prox){
  int idx = blockIdx.x*256 + threadIdx.x;
  int b = idx >> 16, p = idx & 65535, i = p >> 8, j = p & 255;
  int s = seg[idx];
  int base = b << 11;
  mask[base + s] = 1.f;
  if(j < 255){
    int s2 = seg[idx+1];
    if(s != s2 && s != 0 && s2 != 0){
      atomicOr(&prox[((size_t)(base+s))*64  + (s2>>5)], 1u<<(s2&31));
      atomicOr(&prox[((size_t)(base+s2))*64 + (s >>5)], 1u<<(s &31));
    }
  }
  if(i < 255){
    int s2 = seg[idx+256];
    if(s != s2 && s != 0 && s2 != 0){
      atomicOr(&prox[((size_t)(base+s))*64  + (s2>>5)], 1u<<(s2&31));
      atomicOr(&prox[((size_t)(base+s2))*64 + (s >>5)], 1u<<(s &31));
    }
  }
}

// ---- Csim GEMM: writes NORMALIZED s, colsum partials, bf16 xT ----
__global__ __launch_bounds__(256) void k_csim(const float* __restrict__ x,
                                              const float* __restrict__ kn,
                                              float* __restrict__ Sout,
                                              unsigned short* __restrict__ xTbf,
                                              float* __restrict__ part){
  __shared__ float xT[32*68];
  __shared__ float kT[32*68];
  __shared__ float xinvS[64];
  __shared__ float csh[16*64];
  int t = threadIdx.x;
  int m0 = blockIdx.x * 64;
  float acc[4][4] = {};
  int mload = t>>2, koff = (t&3)*8;
  int mb = (t>>4)*4, rb = (t&15)*4;
  float ssq = 0.f;
  for(int c=0;c<12;c++){
    int k0 = c*32;
    __syncthreads();
    const float4* xg = (const float4*)(x + (size_t)(m0+mload)*ND + k0 + koff);
    float4 a = xg[0], bq = xg[1];
    ssq += a.x*a.x + a.y*a.y + a.z*a.z + a.w*a.w
         + bq.x*bq.x + bq.y*bq.y + bq.z*bq.z + bq.w*bq.w;
    xT[(koff+0)*68+mload]=a.x;  xT[(koff+1)*68+mload]=a.y;  xT[(koff+2)*68+mload]=a.z;  xT[(koff+3)*68+mload]=a.w;
    xT[(koff+4)*68+mload]=bq.x; xT[(koff+5)*68+mload]=bq.y; xT[(koff+6)*68+mload]=bq.z; xT[(koff+7)*68+mload]=bq.w;
    const float4* kg = (const float4*)(kn + mload*ND + k0 + koff);
    float4 ka = kg[0], kb = kg[1];
    kT[(koff+0)*68+mload]=ka.x; kT[(koff+1)*68+mload]=ka.y; kT[(koff+2)*68+mload]=ka.z; kT[(koff+3)*68+mload]=ka.w;
    kT[(koff+4)*68+mload]=kb.x; kT[(koff+5)*68+mload]=kb.y; kT[(koff+6)*68+mload]=kb.z; kT[(koff+7)*68+mload]=kb.w;
    __syncthreads();
    {
      int k2 = t>>3, mo = (t&7)*8;
      const float* src = &xT[k2*68 + mo];
      float4 aa = *(const float4*)src;
      float4 bb = *(const float4*)(src+4);
      uint4 o;
      o.x = (unsigned)f2bf(aa.x) | ((unsigned)f2bf(aa.y)<<16);
      o.y = (unsigned)f2bf(aa.z) | ((unsigned)f2bf(aa.w)<<16);
      o.z = (unsigned)f2bf(bb.x) | ((unsigned)f2bf(bb.y)<<16);
      o.w = (unsigned)f2bf(bb.z) | ((unsigned)f2bf(bb.w)<<16);
      int bb2 = m0 >> 11, ml = m0 & 2047;
      *(uint4*)(xTbf + ((size_t)(bb2*ND + k0 + k2))*NN + ml + mo) = o;
    }
    for(int k=0;k<32;k++){
      float xv[4], kv[4];
      *(float4*)xv = *(const float4*)&xT[k*68+mb];
      *(float4*)kv = *(const float4*)&kT[k*68+rb];
      #pragma unroll
      for(int mi=0;mi<4;mi++)
        #pragma unroll
        for(int ri=0;ri<4;ri++) acc[mi][ri] += xv[mi]*kv[ri];
    }
  }
  ssq += __shfl_xor(ssq,1,64);
  ssq += __shfl_xor(ssq,2,64);
  if((t&3)==0) xinvS[mload] = 1.f / fmaxf(sqrtf(ssq), 1e-8f);
  __syncthreads();
  // epilogue: raw -> row-normalized s (rowsum over the 16-lane rb group)
  float sv[4][4];
  #pragma unroll
  for(int mi=0;mi<4;mi++){
    float xin = xinvS[mb+mi];
    float rsum = 0.f;
    #pragma unroll
    for(int ri=0;ri<4;ri++){
      float vv = (acc[mi][ri]*xin + 1.f)*0.5f;
      sv[mi][ri] = vv; rsum += vv;
    }
    rsum += __shfl_xor(rsum,1,64);
    rsum += __shfl_xor(rsum,2,64);
    rsum += __shfl_xor(rsum,4,64);
    rsum += __shfl_xor(rsum,8,64);
    float inv = 1.f/rsum;
    #pragma unroll
    for(int ri=0;ri<4;ri++) sv[mi][ri] *= inv;
    *(float4*)&Sout[(size_t)(m0+mb+mi)*NR + rb] = *(const float4*)sv[mi];
  }
  // colsum partial for this block's 64 nodes (no atomics: fully-written array)
  {
    float4 pc;
    pc.x = sv[0][0]+sv[1][0]+sv[2][0]+sv[3][0];
    pc.y = sv[0][1]+sv[1][1]+sv[2][1]+sv[3][1];
    pc.z = sv[0][2]+sv[1][2]+sv[2][2]+sv[3][2];
    pc.w = sv[0][3]+sv[1][3]+sv[2][3]+sv[3][3];
    *(float4*)&csh[(t>>4)*64 + rb] = pc;
  }
  __syncthreads();
  if(t < 64){
    float a = 0.f;
    #pragma unroll
    for(int g=0;g<16;g++) a += csh[g*64 + t];
    part[(size_t)blockIdx.x*64 + t] = a;        // part[b*32+chunk][r]
  }
}

// ---- DEC KL loss (partial stores) + C=softmax(s) in place + Kbf ----
__global__ void k_lossfc(float* Smat, const float* __restrict__ part,
                         const float* __restrict__ mask,
                         float* __restrict__ klp, float* __restrict__ mp,
                         unsigned short* __restrict__ Kbf){
  __shared__ float shk[4], shm[4];
  int w = threadIdx.x>>6, l = threadIdx.x&63;
  int node = blockIdx.x*4 + w;
  int b = node >> 11;
  float s = Smat[(size_t)node*NR + l];
  float csm = 0.f;
  #pragma unroll
  for(int c=0;c<32;c++) csm += part[(size_t)((b<<5)+c)*64 + l];
  float p = s*s/(csm + 1e-8f);
  float ps = wsum(p);
  float P = p/(ps + 1e-8f);
  float term = P*(logf(P + 1e-8f) - logf(s + 1e-8f));
  float kl = wsum(term);
  if(l==0){ float mv = mask[node]; shk[w] = kl*mv; shm[w] = mv; }
  float mx = wmax(s);
  float e = expf(s - mx);
  float Z = wsum(e);
  float c = e / Z;
  float cn2 = wsum(c*c);
  Smat[(size_t)node*NR + l] = c;
  Kbf[(size_t)node*NR + l] = f2bf(c * rsqrtf(cn2));
  __syncthreads();
  if(threadIdx.x==0){
    klp[blockIdx.x] = shk[0]+shk[1]+shk[2]+shk[3];
    mp [blockIdx.x] = shm[0]+shm[1]+shm[2]+shm[3];
  }
}

// ---- FUSED QK+PV: out = diag(1/(P*1)) P X with P computed per-tile in LDS ----
// grid 512: b=bid&7 (XCD-local batch), nt=(bid>>3)&31 (64-row tile), ds=bid>>8
// (192-col half). 4 waves/block, 2 blocks/CU.
// Per K-tile kt (64 nodes):
//   QK phase (proven k_qk code): wave w computes P rows w*16..+16 (8 MFMA,
//     Chat·Chat^T over R=64), masks with prox bits (+diag when nt==kt),
//     writes bf16 to Plds[buf] (stride 72: bank-balanced for both the b16
//     scatter writes and the b128 A-fragment reads).
//   PV phase: wave w = (rgrp=w>>1, cgrp=w&1) owns 32 rows x 96 cols;
//     A-frags from Plds (LDS latency, not HBM), B-frags = xT (L2-resident),
//     24 MFMA + 4 rowsum-MFMA (ones fragment).
// Double-buffered Plds + cross-barrier prefetch: the NEXT tile's xT/Kbf/prox
// loads are issued before __syncthreads (loads cannot move across the
// barrier -> latency pinned under this tile's MFMAs; fixes round-1's
// compiler-defeated register prefetch).
__global__ __launch_bounds__(256, 2) void k_qkpv(const unsigned short* __restrict__ Kbf,
                                                 const unsigned* __restrict__ prox,
                                                 const unsigned short* __restrict__ xTbf,
                                                 float* __restrict__ out){
  __shared__ short Pl[2][64*72];
  int tid = threadIdx.x;
  int w = tid>>6, l = tid&63, q = l>>4, li = l&15;
  int b  = blockIdx.x & 7;
  int nt = (blockIdx.x>>3) & 31;
  int ds = blockIdx.x >> 8;            // 0..1
  const unsigned short* Kb   = Kbf  + (size_t)b*NN*NR;
  const unsigned*       prxR = prox + (size_t)b*NN*64;
  const unsigned short* xTb  = xTbf + (size_t)b*ND*NN;

  // QK A fragments (loop-invariant): Chat rows nt*64 + w*16 + li
  int arow = nt*64 + w*16 + li;
  bf16x8 af0 = *(const bf16x8*)(Kb + (size_t)arow*NR + q*8);
  bf16x8 af1 = *(const bf16x8*)(Kb + (size_t)arow*NR + 32 + q*8);

  // PV tile assignment
  int rgrp = w>>1, cgrp = w&1;
  int dcb = ds*192 + cgrp*96;

  f32x4 acc[2][6];
  #pragma unroll
  for(int nc=0;nc<2;nc++)
    #pragma unroll
    for(int t=0;t<6;t++) acc[nc][t] = (f32x4)(0.f);
  f32x4 rsacc[2] = {(f32x4)(0.f),(f32x4)(0.f)};
  bf16x8 ones;
  #pragma unroll
  for(int i=0;i<8;i++) ones[i] = (short)0x3F80;   // bf16 1.0

  bf16x8 qb[4][2]; uint2 pw[4];
  bf16x8 bvA[6][2], bvB[6][2];

  // ---- loads for one QK tile ----
#define QK_LOAD(KT) {                                                          \
    _Pragma("unroll") for(int f=0;f<4;f++){                                    \
      const unsigned short* p = Kb + (size_t)((KT)*64 + f*16 + li)*NR + q*8;   \
      qb[f][0] = *(const bf16x8*)p; qb[f][1] = *(const bf16x8*)(p + 32);       \
    }                                                                          \
    _Pragma("unroll") for(int r=0;r<4;r++)                                     \
      pw[r] = *(const uint2*)&prxR[(size_t)(nt*64 + w*16 + q*4 + r)*64 + (KT)*2]; \
  }
  // ---- QK compute + mask + LDS write (tile KT -> buffer PB) ----
#define QK_TILE(KT, PB) {                                                      \
    f32x4 pacc[4] = {(f32x4)(0.f),(f32x4)(0.f),(f32x4)(0.f),(f32x4)(0.f)};     \
    _Pragma("unroll") for(int f=0;f<4;f++){                                    \
      pacc[f] = __builtin_amdgcn_mfma_f32_16x16x32_bf16(af0, qb[f][0], pacc[f], 0,0,0); \
      pacc[f] = __builtin_amdgcn_mfma_f32_16x16x32_bf16(af1, qb[f][1], pacc[f], 0,0,0); \
    }                                                                          \
    _Pragma("unroll") for(int r=0;r<4;r++){                                    \
      int lrow = w*16 + q*4 + r;                                               \
      uint2 mw = pw[r];                                                        \
      if(nt==(KT)){                                                            \
        if((lrow>>5)==0) mw.x |= 1u<<(lrow&31); else mw.y |= 1u<<(lrow&31);    \
      }                                                                        \
      _Pragma("unroll") for(int f=0;f<4;f++){                                  \
        unsigned wd = (f<2) ? mw.x : mw.y;                                     \
        float v = ((wd >> ((f&1)*16 + li)) & 1u) ? pacc[f][r] : 0.f;           \
        Pl[PB][lrow*72 + f*16 + li] = (short)f2bf(v);                          \
      }                                                                        \
    }                                                                          \
  }
  // ---- PV-B loads (xT fragments) for tile KT into BV ----
#define PV_LOAD(KT, BV) {                                                      \
    _Pragma("unroll") for(int t=0;t<6;t++){                                    \
      const unsigned short* p = xTb + (size_t)(dcb + t*16 + li)*NN + (KT)*64 + q*8; \
      BV[t][0] = *(const bf16x8*)p; BV[t][1] = *(const bf16x8*)(p + 32);       \
    }                                                                          \
  }
  // ---- PV compute: consume buffer PB with fragments BV ----
#define PV_TILE(PB, BV) {                                                      \
    _Pragma("unroll") for(int k2=0;k2<2;k2++){                                 \
      bf16x8 a0 = *(const bf16x8*)&Pl[PB][(rgrp*32 +      li)*72 + k2*32 + q*8]; \
      bf16x8 a1 = *(const bf16x8*)&Pl[PB][(rgrp*32 + 16 + li)*72 + k2*32 + q*8]; \
      _Pragma("unroll") for(int t=0;t<6;t++){                                  \
        acc[0][t] = __builtin_amdgcn_mfma_f32_16x16x32_bf16(a0, BV[t][k2], acc[0][t], 0,0,0); \
        acc[1][t] = __builtin_amdgcn_mfma_f32_16x16x32_bf16(a1, BV[t][k2], acc[1][t], 0,0,0); \
      }                                                                        \
      rsacc[0] = __builtin_amdgcn_mfma_f32_16x16x32_bf16(a0, ones, rsacc[0], 0,0,0); \
      rsacc[1] = __builtin_amdgcn_mfma_f32_16x16x32_bf16(a1, ones, rsacc[1], 0,0,0); \
    }                                                                          \
  }

  // ---- prologue: tile 0 -> buf0, PV-B(0) -> bvA ----
  QK_LOAD(0);
  QK_TILE(0, 0);
  PV_LOAD(0, bvA);
  __syncthreads();

  for(int kt=0; kt<32; kt+=2){
    // even body: consume buf0/bvA; prefetch tile kt+1 -> buf1/bvB
    PV_LOAD(kt+1, bvB);
    QK_LOAD(kt+1);
    PV_TILE(0, bvA);
    QK_TILE(kt+1, 1);
    __syncthreads();
    // odd body: consume buf1/bvB; prefetch tile kt+2 -> buf0/bvA (guarded)
    if(kt+2 < 32){
      PV_LOAD(kt+2, bvA);
      QK_LOAD(kt+2);
    }
    PV_TILE(1, bvB);
    if(kt+2 < 32){
      QK_TILE(kt+2, 0);
    }
    __syncthreads();
  }

  // ---- epilogue: row-normalize and store ----
  #pragma unroll
  for(int nc=0;nc<2;nc++)
    #pragma unroll
    for(int r=0;r<4;r++){
      int row = nt*64 + rgrp*32 + nc*16 + q*4 + r;
      float inv = 1.f/(rsacc[nc][r] + 1e-8f);
      float* orow = out + ((size_t)(b*NN + row))*ND + dcb;
      #pragma unroll
      for(int t=0;t<6;t++)
        orow[t*16 + li] = acc[nc][t][r] * inv;
    }
#undef QK_LOAD
#undef QK_TILE
#undef PV_LOAD
#undef PV_TILE
}

// ---- segout; block 0 also reduces the loss partials ----
__global__ void k_segout(const int* __restrict__ seg, float* __restrict__ o,
                         const float* __restrict__ klp, const float* __restrict__ mp,
                         float* __restrict__ outLoss){
  int tid = threadIdx.x;
  int i = blockIdx.x*256 + tid;
  o[i] = (float)seg[i];
  if(blockIdx.x==0){
    __shared__ float sa[4], sm[4];
    float a=0.f, m=0.f;
    for(int k=tid; k<NBLK_LOSS; k+=256){ a += klp[k]; m += mp[k]; }
    a = wsum(a); m = wsum(m);
    if((tid&63)==0){ sa[tid>>6]=a; sm[tid>>6]=m; }
    __syncthreads();
    if(tid==0)
      outLoss[0] = (sa[0]+sa[1]+sa[2]+sa[3])/((sm[0]+sm[1]+sm[2]+sm[3])+1e-8f);
  }
}

extern "C" void kernel_launch(void* const* d_in, const int* in_sizes, int n_in,
                              void* d_out, int out_size, void* d_ws, size_t ws_size,
                              hipStream_t stream) {
  const float* x      = (const float*)d_in[0];
  const int*   seg    = (const int*)d_in[1];
  const float* protos = (const float*)d_in[2];

  float* out     = (float*)d_out;                  // (B,N,D)
  float* outSeg  = out + OUT_ELEMS;                // (B,H,W)
  float* outLoss = outSeg + SEG_ELEMS;             // scalar
  float* outC    = outLoss + 1;                    // (B,N,R)

  // ws layout (Pbf region now unused by the fused pipeline; layout kept)
  unsigned short* xTbf = (unsigned short*)d_ws;            // 8*384*2048 bf16 (12.6MB)
  unsigned short* Kbf  = xTbf + (size_t)NB*ND*NN;          // 8*2048*64 bf16 (2MB)
  unsigned short* Pbf  = Kbf + (size_t)NB*NN*NR;           // (unused, 64MB)
  float* kn      = (float*)(Pbf + (size_t)NB*NN*NN);       // 24576 f32
  float* maskp   = kn + NR*ND;                             // 16384  -- zero region start
  unsigned* prox = (unsigned*)(maskp + NB*NN);             // 8*2048*64 u32 (4MB) -- zero region end
  float* part    = (float*)(prox + (size_t)NB*NN*64);      // 8*32*64 (fully written)
  float* klp     = part + NB*32*64;                        // 4096 (fully written)
  float* mp      = klp + NBLK_LOSS;                        // 4096 (fully written)

  size_t zero_bytes = (size_t)NB*NN*4 + (size_t)NB*NN*64*4;   // maskp + prox
  hipMemsetAsync(maskp, 0, zero_bytes, stream);

  k_proto <<<dim3(NR),           dim3(64),  0, stream>>>(protos, kn);
  k_seg   <<<dim3(NB*65536/256), dim3(256), 0, stream>>>(seg, maskp, prox);
  k_csim  <<<dim3(NB*NN/64),     dim3(256), 0, stream>>>(x, kn, outC, xTbf, part);
  k_lossfc<<<dim3(NBLK_LOSS),    dim3(256), 0, stream>>>(outC, part, maskp, klp, mp, Kbf);
  k_qkpv  <<<dim3(512),          dim3(256), 0, stream>>>(Kbf, prox, xTbf, out);
  k_segout<<<dim3(SEG_ELEMS/256),dim3(256), 0, stream>>>(seg, outSeg, klp, mp, outLoss);
}

// Round 3
// 350.357 us; speedup vs baseline: 1.0590x; 1.0590x over previous
//
#include <hip/hip_runtime.h>
#include <hip/hip_bf16.h>

// B=8, N=2048, D=384, R=64, H=W=256.
// Inputs:  x (B,N,D) f32, segments (B,H,W) i32, prototypes (1,R,D) f32.
// Outputs (f32, concat): out (B,N,D) | segments (B,H,W) | loss (1) | C (B,N,R)
//
// Pipeline (8 dispatches, ZERO same-address atomic hotspots):
//   memset(maskp+prox) ; k_proto ; k_seg ; k_csim (S normalized + colsum
//   partials + bf16 xT) ; k_lossfc (loss partials + C + Kbf) ; k_qk (P=mask.*
//   ChatChat^T bf16 -> ws) ; k_pv (out = diag(1/(P*1)) P X, rowsum via
//   ones-fragment MFMA, INLINE-ASM depth-4 load pipeline w/ counted vmcnt) ;
//   k_segout (+ loss final reduce in block 0).
//
// Round-2 lesson: fusing QK into PV with per-tile __syncthreads loses — hipcc
// drains vmcnt(0) before every s_barrier, serializing all prefetch. k_pv is
// barrier-free, so counted-vmcnt asm pipelining applies cleanly there instead.
#define NB 8
#define NN 2048
#define ND 384
#define NR 64
#define OUT_ELEMS (NB*NN*ND)        // 6291456
#define SEG_ELEMS (NB*256*256)      // 524288
#define NBLK_LOSS (NB*NN/4)         // 4096

typedef float  f32x4  __attribute__((ext_vector_type(4)));
typedef short  bf16x8 __attribute__((ext_vector_type(8)));

__device__ inline float wsum(float v){
  #pragma unroll
  for(int o=32;o;o>>=1) v += __shfl_xor(v,o,64);
  return v;
}
__device__ inline float wmax(float v){
  #pragma unroll
  for(int o=32;o;o>>=1) v = fmaxf(v,__shfl_xor(v,o,64));
  return v;
}
__device__ inline unsigned short f2bf(float f){
  unsigned u = __float_as_uint(f);
  return (unsigned short)((u + 0x8000u) >> 16);
}

// ---- normalize prototypes -> kn (f32, unit rows) ----
__global__ void k_proto(const float* __restrict__ protos, float* __restrict__ kn){
  int r = blockIdx.x, l = threadIdx.x;
  float v[6]; float ss = 0.f;
  #pragma unroll
  for(int i=0;i<6;i++){ v[i] = protos[r*ND + l*6 + i]; ss += v[i]*v[i]; }
  ss = wsum(ss);
  float inv = 1.f / fmaxf(sqrtf(ss), 1e-8f);
  #pragma unroll
  for(int i=0;i<6;i++) kn[r*ND + l*6 + i] = v[i]*inv;
}

// ---- segments -> node mask + prox bitmask rows (64 u32/node) ----
__global__ void k_seg(const int* __restrict__ seg, float* __restrict__ mask, unsigned* prox){
  int idx = blockIdx.x*256 + threadIdx.x;
  int b = idx >> 16, p = idx & 65535, i = p >> 8, j = p & 255;
  int s = seg[idx];
  int base = b << 11;
  mask[base + s] = 1.f;
  if(j < 255){
    int s2 = seg[idx+1];
    if(s != s2 && s != 0 && s2 != 0){
      atomicOr(&prox[((size_t)(base+s))*64  + (s2>>5)], 1u<<(s2&31));
      atomicOr(&prox[((size_t)(base+s2))*64 + (s >>5)], 1u<<(s &31));
    }
  }
  if(i < 255){
    int s2 = seg[idx+256];
    if(s != s2 && s != 0 && s2 != 0){
      atomicOr(&prox[((size_t)(base+s))*64  + (s2>>5)], 1u<<(s2&31));
      atomicOr(&prox[((size_t)(base+s2))*64 + (s >>5)], 1u<<(s &31));
    }
  }
}

// ---- Csim GEMM: writes NORMALIZED s, colsum partials, bf16 xT ----
__global__ __launch_bounds__(256) void k_csim(const float* __restrict__ x,
                                              const float* __restrict__ kn,
                                              float* __restrict__ Sout,
                                              unsigned short* __restrict__ xTbf,
                                              float* __restrict__ part){
  __shared__ float xT[32*68];
  __shared__ float kT[32*68];
  __shared__ float xinvS[64];
  __shared__ float csh[16*64];
  int t = threadIdx.x;
  int m0 = blockIdx.x * 64;
  float acc[4][4] = {};
  int mload = t>>2, koff = (t&3)*8;
  int mb = (t>>4)*4, rb = (t&15)*4;
  float ssq = 0.f;
  for(int c=0;c<12;c++){
    int k0 = c*32;
    __syncthreads();
    const float4* xg = (const float4*)(x + (size_t)(m0+mload)*ND + k0 + koff);
    float4 a = xg[0], bq = xg[1];
    ssq += a.x*a.x + a.y*a.y + a.z*a.z + a.w*a.w
         + bq.x*bq.x + bq.y*bq.y + bq.z*bq.z + bq.w*bq.w;
    xT[(koff+0)*68+mload]=a.x;  xT[(koff+1)*68+mload]=a.y;  xT[(koff+2)*68+mload]=a.z;  xT[(koff+3)*68+mload]=a.w;
    xT[(koff+4)*68+mload]=bq.x; xT[(koff+5)*68+mload]=bq.y; xT[(koff+6)*68+mload]=bq.z; xT[(koff+7)*68+mload]=bq.w;
    const float4* kg = (const float4*)(kn + mload*ND + k0 + koff);
    float4 ka = kg[0], kb = kg[1];
    kT[(koff+0)*68+mload]=ka.x; kT[(koff+1)*68+mload]=ka.y; kT[(koff+2)*68+mload]=ka.z; kT[(koff+3)*68+mload]=ka.w;
    kT[(koff+4)*68+mload]=kb.x; kT[(koff+5)*68+mload]=kb.y; kT[(koff+6)*68+mload]=kb.z; kT[(koff+7)*68+mload]=kb.w;
    __syncthreads();
    {
      int k2 = t>>3, mo = (t&7)*8;
      const float* src = &xT[k2*68 + mo];
      float4 aa = *(const float4*)src;
      float4 bb = *(const float4*)(src+4);
      uint4 o;
      o.x = (unsigned)f2bf(aa.x) | ((unsigned)f2bf(aa.y)<<16);
      o.y = (unsigned)f2bf(aa.z) | ((unsigned)f2bf(aa.w)<<16);
      o.z = (unsigned)f2bf(bb.x) | ((unsigned)f2bf(bb.y)<<16);
      o.w = (unsigned)f2bf(bb.z) | ((unsigned)f2bf(bb.w)<<16);
      int bb2 = m0 >> 11, ml = m0 & 2047;
      *(uint4*)(xTbf + ((size_t)(bb2*ND + k0 + k2))*NN + ml + mo) = o;
    }
    for(int k=0;k<32;k++){
      float xv[4], kv[4];
      *(float4*)xv = *(const float4*)&xT[k*68+mb];
      *(float4*)kv = *(const float4*)&kT[k*68+rb];
      #pragma unroll
      for(int mi=0;mi<4;mi++)
        #pragma unroll
        for(int ri=0;ri<4;ri++) acc[mi][ri] += xv[mi]*kv[ri];
    }
  }
  ssq += __shfl_xor(ssq,1,64);
  ssq += __shfl_xor(ssq,2,64);
  if((t&3)==0) xinvS[mload] = 1.f / fmaxf(sqrtf(ssq), 1e-8f);
  __syncthreads();
  // epilogue: raw -> row-normalized s (rowsum over the 16-lane rb group)
  float sv[4][4];
  #pragma unroll
  for(int mi=0;mi<4;mi++){
    float xin = xinvS[mb+mi];
    float rsum = 0.f;
    #pragma unroll
    for(int ri=0;ri<4;ri++){
      float vv = (acc[mi][ri]*xin + 1.f)*0.5f;
      sv[mi][ri] = vv; rsum += vv;
    }
    rsum += __shfl_xor(rsum,1,64);
    rsum += __shfl_xor(rsum,2,64);
    rsum += __shfl_xor(rsum,4,64);
    rsum += __shfl_xor(rsum,8,64);
    float inv = 1.f/rsum;
    #pragma unroll
    for(int ri=0;ri<4;ri++) sv[mi][ri] *= inv;
    *(float4*)&Sout[(size_t)(m0+mb+mi)*NR + rb] = *(const float4*)sv[mi];
  }
  // colsum partial for this block's 64 nodes (no atomics: fully-written array)
  {
    float4 pc;
    pc.x = sv[0][0]+sv[1][0]+sv[2][0]+sv[3][0];
    pc.y = sv[0][1]+sv[1][1]+sv[2][1]+sv[3][1];
    pc.z = sv[0][2]+sv[1][2]+sv[2][2]+sv[3][2];
    pc.w = sv[0][3]+sv[1][3]+sv[2][3]+sv[3][3];
    *(float4*)&csh[(t>>4)*64 + rb] = pc;
  }
  __syncthreads();
  if(t < 64){
    float a = 0.f;
    #pragma unroll
    for(int g=0;g<16;g++) a += csh[g*64 + t];
    part[(size_t)blockIdx.x*64 + t] = a;        // part[b*32+chunk][r]
  }
}

// ---- DEC KL loss (partial stores) + C=softmax(s) in place + Kbf ----
__global__ void k_lossfc(float* Smat, const float* __restrict__ part,
                         const float* __restrict__ mask,
                         float* __restrict__ klp, float* __restrict__ mp,
                         unsigned short* __restrict__ Kbf){
  __shared__ float shk[4], shm[4];
  int w = threadIdx.x>>6, l = threadIdx.x&63;
  int node = blockIdx.x*4 + w;
  int b = node >> 11;
  float s = Smat[(size_t)node*NR + l];
  float csm = 0.f;
  #pragma unroll
  for(int c=0;c<32;c++) csm += part[(size_t)((b<<5)+c)*64 + l];
  float p = s*s/(csm + 1e-8f);
  float ps = wsum(p);
  float P = p/(ps + 1e-8f);
  float term = P*(logf(P + 1e-8f) - logf(s + 1e-8f));
  float kl = wsum(term);
  if(l==0){ float mv = mask[node]; shk[w] = kl*mv; shm[w] = mv; }
  float mx = wmax(s);
  float e = expf(s - mx);
  float Z = wsum(e);
  float c = e / Z;
  float cn2 = wsum(c*c);
  Smat[(size_t)node*NR + l] = c;
  Kbf[(size_t)node*NR + l] = f2bf(c * rsqrtf(cn2));
  __syncthreads();
  if(threadIdx.x==0){
    klp[blockIdx.x] = shk[0]+shk[1]+shk[2]+shk[3];
    mp [blockIdx.x] = shm[0]+shm[1]+shm[2]+shm[3];
  }
}

// ---- pass A: P tile (64x64) = mask .* (Chat Chat^T), bf16 -> ws ----
// grid 8192: b=bid&7, qt=(bid>>3)&31, kt=bid>>8. One barrier per block.
__global__ __launch_bounds__(256) void k_qk(const unsigned short* __restrict__ Kbf,
                                            const unsigned* __restrict__ prox,
                                            unsigned short* __restrict__ Pbf){
  __shared__ short Plds[64*72];
  int tid = threadIdx.x;
  int w = tid>>6, l = tid&63, q = l>>4, li = l&15;
  int b  = blockIdx.x & 7;
  int qt = (blockIdx.x>>3) & 31;
  int kt = blockIdx.x >> 8;
  const unsigned short* Kb = Kbf + (size_t)b*NN*NR;

  int arow = qt*64 + w*16 + li;
  bf16x8 af[2];
  af[0] = *(const bf16x8*)(Kb + (size_t)arow*NR + q*8);
  af[1] = *(const bf16x8*)(Kb + (size_t)arow*NR + 32 + q*8);
  f32x4 pacc[4] = {(f32x4)(0.f),(f32x4)(0.f),(f32x4)(0.f),(f32x4)(0.f)};
  #pragma unroll
  for(int f=0;f<4;f++){
    int brow = kt*64 + f*16 + li;
    bf16x8 b0 = *(const bf16x8*)(Kb + (size_t)brow*NR + q*8);
    bf16x8 b1 = *(const bf16x8*)(Kb + (size_t)brow*NR + 32 + q*8);
    pacc[f] = __builtin_amdgcn_mfma_f32_16x16x32_bf16(af[0], b0, pacc[f], 0,0,0);
    pacc[f] = __builtin_amdgcn_mfma_f32_16x16x32_bf16(af[1], b1, pacc[f], 0,0,0);
  }
  #pragma unroll
  for(int r=0;r<4;r++){
    int lrow = w*16 + q*4 + r;
    int grow = qt*64 + lrow;
    uint2 mw = *(const uint2*)(prox + ((size_t)(b*NN + grow))*64 + kt*2);
    if(qt==kt){
      if((lrow>>5)==0) mw.x |= 1u<<(lrow&31); else mw.y |= 1u<<(lrow&31);
    }
    #pragma unroll
    for(int f=0;f<4;f++){
      unsigned wd = (f<2) ? mw.x : mw.y;
      float v = ((wd >> ((f&1)*16 + li)) & 1u) ? pacc[f][r] : 0.f;
      Plds[lrow*72 + f*16 + li] = (short)f2bf(v);
    }
  }
  __syncthreads();
  {
    int row = tid>>2, sg = tid&3;
    const uint4* src = (const uint4*)&Plds[row*72 + sg*16];
    unsigned short* dst = Pbf + ((size_t)(b*NN + qt*64 + row))*NN + kt*64 + sg*16;
    uint4 v0 = src[0], v1 = *(const uint4*)((const short*)src + 8);
    *(uint4*)dst = v0;
    *(uint4*)(dst + 8) = v1;
  }
}

// ---- pass B: out = diag(1/(P*1)) P X. Streaming, no LDS/barriers/atomics ----
// rowsum via ones-fragment MFMA. grid 512: b=bid&7 (== XCD id for round-robin
// dispatch -> all blocks of batch b share an XCD L2; P rows hit L2 on the
// ds=0/ds=1 re-read), nt, ds.
//
// INLINE-ASM depth-4 load pipeline: 28 global_load_dwordx4 (4 slots x 7 frags)
// kept in flight per wave; consumption gated by counted `s_waitcnt vmcnt(21)`
// (vmcnt is oldest-ordered: retires exactly the oldest slot) + sched_barrier(0)
// so MFMAs can't hoist above the wait (rule #18). asm volatile loads are
// opaque to the scheduler -> cannot be sunk back to their uses (which killed
// the round-1 source-level prefetch; VGPR stayed 100). WAR on slot regs is
// register-dependency-tracked; in-order issue means MFMAs read operands long
// before the refill's writeback lands.
__global__ __launch_bounds__(256, 2) void k_pv(const unsigned short* __restrict__ Pbf,
                                               const unsigned short* __restrict__ xTbf,
                                               float* __restrict__ out){
  int tid = threadIdx.x;
  int w = tid>>6, l = tid&63, q = l>>4, li = l&15;
  int b  = blockIdx.x & 7;
  int nt = (blockIdx.x>>3) & 31;
  int ds = blockIdx.x >> 8;
  int base = nt*64;
  int dcb = ds*192 + w*48;
  const unsigned short* Pb  = Pbf  + (size_t)b*NN*NN;
  const unsigned short* xTb = xTbf + (size_t)b*ND*NN;

  f32x4 acc[4][3];
  #pragma unroll
  for(int nc=0;nc<4;nc++)
    #pragma unroll
    for(int t=0;t<3;t++) acc[nc][t] = (f32x4)(0.f);
  f32x4 rsacc[4] = {(f32x4)(0.f),(f32x4)(0.f),(f32x4)(0.f),(f32x4)(0.f)};
  bf16x8 ones;
  #pragma unroll
  for(int i=0;i<8;i++) ones[i] = (short)0x3F80;   // bf16 1.0

  // 7 per-fragment base pointers (advance by 128 elems = 256 B per macro-iter)
  const unsigned short* pa0 = Pb  + (size_t)(base + 0*16 + li)*NN + q*8;
  const unsigned short* pa1 = Pb  + (size_t)(base + 1*16 + li)*NN + q*8;
  const unsigned short* pa2 = Pb  + (size_t)(base + 2*16 + li)*NN + q*8;
  const unsigned short* pa3 = Pb  + (size_t)(base + 3*16 + li)*NN + q*8;
  const unsigned short* pb0 = xTb + (size_t)(dcb  + 0*16 + li)*NN + q*8;
  const unsigned short* pb1 = xTb + (size_t)(dcb  + 1*16 + li)*NN + q*8;
  const unsigned short* pb2 = xTb + (size_t)(dcb  + 2*16 + li)*NN + q*8;

  bf16x8 sA[4][4], sB[4][3];   // [slot][frag] -- all indexing static

#define GL(dst, p, O) \
  asm volatile("global_load_dwordx4 %0, %1, off offset:" O \
               : "=&v"(dst) : "v"(p))
#define LOADS(S, O) { \
    GL(sA[S][0], pa0, O); GL(sA[S][1], pa1, O); \
    GL(sA[S][2], pa2, O); GL(sA[S][3], pa3, O); \
    GL(sB[S][0], pb0, O); GL(sB[S][1], pb1, O); GL(sB[S][2], pb2, O); }
#define CONS(S, VM) { \
    asm volatile("s_waitcnt vmcnt(" #VM ")" ::: "memory"); \
    __builtin_amdgcn_sched_barrier(0); \
    _Pragma("unroll") for(int nc=0;nc<4;nc++){ \
      _Pragma("unroll") for(int t=0;t<3;t++) \
        acc[nc][t] = __builtin_amdgcn_mfma_f32_16x16x32_bf16(sA[S][nc], sB[S][t], acc[nc][t], 0,0,0); \
      rsacc[nc] = __builtin_amdgcn_mfma_f32_16x16x32_bf16(sA[S][nc], ones, rsacc[nc], 0,0,0); \
    } }

  // prologue: fill slots with k = 0,32,64,96 (byte offsets 0,64,128,192)
  LOADS(0, "0"); LOADS(1, "64"); LOADS(2, "128"); LOADS(3, "192");

  // 15 macro-iters: consume k=it*128..+127, refill k+128..+255 (offsets 256..448)
  #pragma unroll 1
  for(int it=0; it<15; ++it){
    CONS(0, 21); LOADS(0, "256");
    CONS(1, 21); LOADS(1, "320");
    CONS(2, 21); LOADS(2, "384");
    CONS(3, 21); LOADS(3, "448");
    pa0 += 128; pa1 += 128; pa2 += 128; pa3 += 128;
    pb0 += 128; pb1 += 128; pb2 += 128;
  }
  // epilogue tile (k = 1920..2047): drain 28 -> 0
  CONS(0, 21); CONS(1, 14); CONS(2, 7); CONS(3, 0);

#undef GL
#undef LOADS
#undef CONS

  #pragma unroll
  for(int nc=0;nc<4;nc++)
    #pragma unroll
    for(int r=0;r<4;r++){
      int row = base + nc*16 + q*4 + r;
      float inv = 1.f/(rsacc[nc][r] + 1e-8f);
      float* orow = out + ((size_t)(b*NN + row))*ND + dcb;
      #pragma unroll
      for(int t=0;t<3;t++)
        orow[t*16 + li] = acc[nc][t][r] * inv;
    }
}

// ---- segout; block 0 also reduces the loss partials ----
__global__ void k_segout(const int* __restrict__ seg, float* __restrict__ o,
                         const float* __restrict__ klp, const float* __restrict__ mp,
                         float* __restrict__ outLoss){
  int tid = threadIdx.x;
  int i = blockIdx.x*256 + tid;
  o[i] = (float)seg[i];
  if(blockIdx.x==0){
    __shared__ float sa[4], sm[4];
    float a=0.f, m=0.f;
    for(int k=tid; k<NBLK_LOSS; k+=256){ a += klp[k]; m += mp[k]; }
    a = wsum(a); m = wsum(m);
    if((tid&63)==0){ sa[tid>>6]=a; sm[tid>>6]=m; }
    __syncthreads();
    if(tid==0)
      outLoss[0] = (sa[0]+sa[1]+sa[2]+sa[3])/((sm[0]+sm[1]+sm[2]+sm[3])+1e-8f);
  }
}

extern "C" void kernel_launch(void* const* d_in, const int* in_sizes, int n_in,
                              void* d_out, int out_size, void* d_ws, size_t ws_size,
                              hipStream_t stream) {
  const float* x      = (const float*)d_in[0];
  const int*   seg    = (const int*)d_in[1];
  const float* protos = (const float*)d_in[2];

  float* out     = (float*)d_out;                  // (B,N,D)
  float* outSeg  = out + OUT_ELEMS;                // (B,H,W)
  float* outLoss = outSeg + SEG_ELEMS;             // scalar
  float* outC    = outLoss + 1;                    // (B,N,R)

  // ws layout (~83 MB)
  unsigned short* xTbf = (unsigned short*)d_ws;            // 8*384*2048 bf16 (12.6MB)
  unsigned short* Kbf  = xTbf + (size_t)NB*ND*NN;          // 8*2048*64 bf16 (2MB)
  unsigned short* Pbf  = Kbf + (size_t)NB*NN*NR;           // 8*2048*2048 bf16 (64MB)
  float* kn      = (float*)(Pbf + (size_t)NB*NN*NN);       // 24576 f32
  float* maskp   = kn + NR*ND;                             // 16384  -- zero region start
  unsigned* prox = (unsigned*)(maskp + NB*NN);             // 8*2048*64 u32 (4MB) -- zero region end
  float* part    = (float*)(prox + (size_t)NB*NN*64);      // 8*32*64 (fully written)
  float* klp     = part + NB*32*64;                        // 4096 (fully written)
  float* mp      = klp + NBLK_LOSS;                        // 4096 (fully written)

  size_t zero_bytes = (size_t)NB*NN*4 + (size_t)NB*NN*64*4;   // maskp + prox
  hipMemsetAsync(maskp, 0, zero_bytes, stream);

  k_proto <<<dim3(NR),           dim3(64),  0, stream>>>(protos, kn);
  k_seg   <<<dim3(NB*65536/256), dim3(256), 0, stream>>>(seg, maskp, prox);
  k_csim  <<<dim3(NB*NN/64),     dim3(256), 0, stream>>>(x, kn, outC, xTbf, part);
  k_lossfc<<<dim3(NBLK_LOSS),    dim3(256), 0, stream>>>(outC, part, maskp, klp, mp, Kbf);
  k_qk    <<<dim3(8192),         dim3(256), 0, stream>>>(Kbf, prox, Pbf);
  k_pv    <<<dim3(512),          dim3(256), 0, stream>>>(Pbf, xTbf, out);
  k_segout<<<dim3(SEG_ELEMS/256),dim3(256), 0, stream>>>(seg, outSeg, klp, mp, outLoss);
}

// Round 4
// 291.467 us; speedup vs baseline: 1.2730x; 1.2020x over previous
//
#include <hip/hip_runtime.h>
#include <hip/hip_bf16.h>

// B=8, N=2048, D=384, R=64, H=W=256.
// Inputs:  x (B,N,D) f32, segments (B,H,W) i32, prototypes (1,R,D) f32.
// Outputs (f32, concat): out (B,N,D) | segments (B,H,W) | loss (1) | C (B,N,R)
//
// Pipeline (8 dispatches):
//   memset(maskp+prox) ; k_proto ; k_seg ; k_csim (S normalized + colsum
//   partials + bf16 xT) ; k_lossfc (loss partials + C + Kbf) ; k_qk (P=mask.*
//   ChatChat^T bf16 -> ws) ; k_pv (out = diag(1/(P*1)) P X — m97-structure
//   LDS-staged GEMM: global_load_lds(16B) + 2 barriers/K-step + ds_read_b128
//   fragments + ones-MFMA rowsum) ; k_segout (+ loss final reduce).
//
// k_pv history: register-direct streaming (3 variants: naive / source
// prefetch / inline-asm counted-vmcnt pipeline) all pinned at 108 us,
// MfmaUtil 12% — per-wave in-order vmcnt retirement can't hide L3/HBM
// latency at 8 waves/CU, and all 4 waves duplicated the A-tile loads.
// LDS staging de-duplicates A, bulk-amortizes the latency, 3 blocks/CU.
#define NB 8
#define NN 2048
#define ND 384
#define NR 64
#define OUT_ELEMS (NB*NN*ND)        // 6291456
#define SEG_ELEMS (NB*256*256)      // 524288
#define NBLK_LOSS (NB*NN/4)         // 4096

typedef float  f32x4  __attribute__((ext_vector_type(4)));
typedef short  bf16x8 __attribute__((ext_vector_type(8)));

__device__ inline float wsum(float v){
  #pragma unroll
  for(int o=32;o;o>>=1) v += __shfl_xor(v,o,64);
  return v;
}
__device__ inline float wmax(float v){
  #pragma unroll
  for(int o=32;o;o>>=1) v = fmaxf(v,__shfl_xor(v,o,64));
  return v;
}
__device__ inline unsigned short f2bf(float f){
  unsigned u = __float_as_uint(f);
  return (unsigned short)((u + 0x8000u) >> 16);
}

// async global->LDS, 16 B per lane; LDS dest is wave-uniform base + lane*16
__device__ __forceinline__ void gl2lds16(const unsigned short* g, unsigned short* s){
  __builtin_amdgcn_global_load_lds(
      (const __attribute__((address_space(1))) unsigned int*)g,
      (__attribute__((address_space(3))) unsigned int*)s,
      16, 0, 0);
}

// ---- normalize prototypes -> kn (f32, unit rows) ----
__global__ void k_proto(const float* __restrict__ protos, float* __restrict__ kn){
  int r = blockIdx.x, l = threadIdx.x;
  float v[6]; float ss = 0.f;
  #pragma unroll
  for(int i=0;i<6;i++){ v[i] = protos[r*ND + l*6 + i]; ss += v[i]*v[i]; }
  ss = wsum(ss);
  float inv = 1.f / fmaxf(sqrtf(ss), 1e-8f);
  #pragma unroll
  for(int i=0;i<6;i++) kn[r*ND + l*6 + i] = v[i]*inv;
}

// ---- segments -> node mask + prox bitmask rows (64 u32/node) ----
__global__ void k_seg(const int* __restrict__ seg, float* __restrict__ mask, unsigned* prox){
  int idx = blockIdx.x*256 + threadIdx.x;
  int b = idx >> 16, p = idx & 65535, i = p >> 8, j = p & 255;
  int s = seg[idx];
  int base = b << 11;
  mask[base + s] = 1.f;
  if(j < 255){
    int s2 = seg[idx+1];
    if(s != s2 && s != 0 && s2 != 0){
      atomicOr(&prox[((size_t)(base+s))*64  + (s2>>5)], 1u<<(s2&31));
      atomicOr(&prox[((size_t)(base+s2))*64 + (s >>5)], 1u<<(s &31));
    }
  }
  if(i < 255){
    int s2 = seg[idx+256];
    if(s != s2 && s != 0 && s2 != 0){
      atomicOr(&prox[((size_t)(base+s))*64  + (s2>>5)], 1u<<(s2&31));
      atomicOr(&prox[((size_t)(base+s2))*64 + (s >>5)], 1u<<(s &31));
    }
  }
}

// ---- Csim GEMM: writes NORMALIZED s, colsum partials, bf16 xT ----
__global__ __launch_bounds__(256) void k_csim(const float* __restrict__ x,
                                              const float* __restrict__ kn,
                                              float* __restrict__ Sout,
                                              unsigned short* __restrict__ xTbf,
                                              float* __restrict__ part){
  __shared__ float xT[32*68];
  __shared__ float kT[32*68];
  __shared__ float xinvS[64];
  __shared__ float csh[16*64];
  int t = threadIdx.x;
  int m0 = blockIdx.x * 64;
  float acc[4][4] = {};
  int mload = t>>2, koff = (t&3)*8;
  int mb = (t>>4)*4, rb = (t&15)*4;
  float ssq = 0.f;
  for(int c=0;c<12;c++){
    int k0 = c*32;
    __syncthreads();
    const float4* xg = (const float4*)(x + (size_t)(m0+mload)*ND + k0 + koff);
    float4 a = xg[0], bq = xg[1];
    ssq += a.x*a.x + a.y*a.y + a.z*a.z + a.w*a.w
         + bq.x*bq.x + bq.y*bq.y + bq.z*bq.z + bq.w*bq.w;
    xT[(koff+0)*68+mload]=a.x;  xT[(koff+1)*68+mload]=a.y;  xT[(koff+2)*68+mload]=a.z;  xT[(koff+3)*68+mload]=a.w;
    xT[(koff+4)*68+mload]=bq.x; xT[(koff+5)*68+mload]=bq.y; xT[(koff+6)*68+mload]=bq.z; xT[(koff+7)*68+mload]=bq.w;
    const float4* kg = (const float4*)(kn + mload*ND + k0 + koff);
    float4 ka = kg[0], kb = kg[1];
    kT[(koff+0)*68+mload]=ka.x; kT[(koff+1)*68+mload]=ka.y; kT[(koff+2)*68+mload]=ka.z; kT[(koff+3)*68+mload]=ka.w;
    kT[(koff+4)*68+mload]=kb.x; kT[(koff+5)*68+mload]=kb.y; kT[(koff+6)*68+mload]=kb.z; kT[(koff+7)*68+mload]=kb.w;
    __syncthreads();
    {
      int k2 = t>>3, mo = (t&7)*8;
      const float* src = &xT[k2*68 + mo];
      float4 aa = *(const float4*)src;
      float4 bb = *(const float4*)(src+4);
      uint4 o;
      o.x = (unsigned)f2bf(aa.x) | ((unsigned)f2bf(aa.y)<<16);
      o.y = (unsigned)f2bf(aa.z) | ((unsigned)f2bf(aa.w)<<16);
      o.z = (unsigned)f2bf(bb.x) | ((unsigned)f2bf(bb.y)<<16);
      o.w = (unsigned)f2bf(bb.z) | ((unsigned)f2bf(bb.w)<<16);
      int bb2 = m0 >> 11, ml = m0 & 2047;
      *(uint4*)(xTbf + ((size_t)(bb2*ND + k0 + k2))*NN + ml + mo) = o;
    }
    for(int k=0;k<32;k++){
      float xv[4], kv[4];
      *(float4*)xv = *(const float4*)&xT[k*68+mb];
      *(float4*)kv = *(const float4*)&kT[k*68+rb];
      #pragma unroll
      for(int mi=0;mi<4;mi++)
        #pragma unroll
        for(int ri=0;ri<4;ri++) acc[mi][ri] += xv[mi]*kv[ri];
    }
  }
  ssq += __shfl_xor(ssq,1,64);
  ssq += __shfl_xor(ssq,2,64);
  if((t&3)==0) xinvS[mload] = 1.f / fmaxf(sqrtf(ssq), 1e-8f);
  __syncthreads();
  // epilogue: raw -> row-normalized s (rowsum over the 16-lane rb group)
  float sv[4][4];
  #pragma unroll
  for(int mi=0;mi<4;mi++){
    float xin = xinvS[mb+mi];
    float rsum = 0.f;
    #pragma unroll
    for(int ri=0;ri<4;ri++){
      float vv = (acc[mi][ri]*xin + 1.f)*0.5f;
      sv[mi][ri] = vv; rsum += vv;
    }
    rsum += __shfl_xor(rsum,1,64);
    rsum += __shfl_xor(rsum,2,64);
    rsum += __shfl_xor(rsum,4,64);
    rsum += __shfl_xor(rsum,8,64);
    float inv = 1.f/rsum;
    #pragma unroll
    for(int ri=0;ri<4;ri++) sv[mi][ri] *= inv;
    *(float4*)&Sout[(size_t)(m0+mb+mi)*NR + rb] = *(const float4*)sv[mi];
  }
  // colsum partial for this block's 64 nodes (no atomics: fully-written array)
  {
    float4 pc;
    pc.x = sv[0][0]+sv[1][0]+sv[2][0]+sv[3][0];
    pc.y = sv[0][1]+sv[1][1]+sv[2][1]+sv[3][1];
    pc.z = sv[0][2]+sv[1][2]+sv[2][2]+sv[3][2];
    pc.w = sv[0][3]+sv[1][3]+sv[2][3]+sv[3][3];
    *(float4*)&csh[(t>>4)*64 + rb] = pc;
  }
  __syncthreads();
  if(t < 64){
    float a = 0.f;
    #pragma unroll
    for(int g=0;g<16;g++) a += csh[g*64 + t];
    part[(size_t)blockIdx.x*64 + t] = a;        // part[b*32+chunk][r]
  }
}

// ---- DEC KL loss (partial stores) + C=softmax(s) in place + Kbf ----
__global__ void k_lossfc(float* Smat, const float* __restrict__ part,
                         const float* __restrict__ mask,
                         float* __restrict__ klp, float* __restrict__ mp,
                         unsigned short* __restrict__ Kbf){
  __shared__ float shk[4], shm[4];
  int w = threadIdx.x>>6, l = threadIdx.x&63;
  int node = blockIdx.x*4 + w;
  int b = node >> 11;
  float s = Smat[(size_t)node*NR + l];
  float csm = 0.f;
  #pragma unroll
  for(int c=0;c<32;c++) csm += part[(size_t)((b<<5)+c)*64 + l];
  float p = s*s/(csm + 1e-8f);
  float ps = wsum(p);
  float P = p/(ps + 1e-8f);
  float term = P*(logf(P + 1e-8f) - logf(s + 1e-8f));
  float kl = wsum(term);
  if(l==0){ float mv = mask[node]; shk[w] = kl*mv; shm[w] = mv; }
  float mx = wmax(s);
  float e = expf(s - mx);
  float Z = wsum(e);
  float c = e / Z;
  float cn2 = wsum(c*c);
  Smat[(size_t)node*NR + l] = c;
  Kbf[(size_t)node*NR + l] = f2bf(c * rsqrtf(cn2));
  __syncthreads();
  if(threadIdx.x==0){
    klp[blockIdx.x] = shk[0]+shk[1]+shk[2]+shk[3];
    mp [blockIdx.x] = shm[0]+shm[1]+shm[2]+shm[3];
  }
}

// ---- pass A: P tile (64x64) = mask .* (Chat Chat^T), bf16 -> ws ----
// grid 8192: b=bid&7, qt=(bid>>3)&31, kt=bid>>8. One barrier per block.
__global__ __launch_bounds__(256) void k_qk(const unsigned short* __restrict__ Kbf,
                                            const unsigned* __restrict__ prox,
                                            unsigned short* __restrict__ Pbf){
  __shared__ short Plds[64*72];
  int tid = threadIdx.x;
  int w = tid>>6, l = tid&63, q = l>>4, li = l&15;
  int b  = blockIdx.x & 7;
  int qt = (blockIdx.x>>3) & 31;
  int kt = blockIdx.x >> 8;
  const unsigned short* Kb = Kbf + (size_t)b*NN*NR;

  int arow = qt*64 + w*16 + li;
  bf16x8 af[2];
  af[0] = *(const bf16x8*)(Kb + (size_t)arow*NR + q*8);
  af[1] = *(const bf16x8*)(Kb + (size_t)arow*NR + 32 + q*8);
  f32x4 pacc[4] = {(f32x4)(0.f),(f32x4)(0.f),(f32x4)(0.f),(f32x4)(0.f)};
  #pragma unroll
  for(int f=0;f<4;f++){
    int brow = kt*64 + f*16 + li;
    bf16x8 b0 = *(const bf16x8*)(Kb + (size_t)brow*NR + q*8);
    bf16x8 b1 = *(const bf16x8*)(Kb + (size_t)brow*NR + 32 + q*8);
    pacc[f] = __builtin_amdgcn_mfma_f32_16x16x32_bf16(af[0], b0, pacc[f], 0,0,0);
    pacc[f] = __builtin_amdgcn_mfma_f32_16x16x32_bf16(af[1], b1, pacc[f], 0,0,0);
  }
  #pragma unroll
  for(int r=0;r<4;r++){
    int lrow = w*16 + q*4 + r;
    int grow = qt*64 + lrow;
    uint2 mw = *(const uint2*)(prox + ((size_t)(b*NN + grow))*64 + kt*2);
    if(qt==kt){
      if((lrow>>5)==0) mw.x |= 1u<<(lrow&31); else mw.y |= 1u<<(lrow&31);
    }
    #pragma unroll
    for(int f=0;f<4;f++){
      unsigned wd = (f<2) ? mw.x : mw.y;
      float v = ((wd >> ((f&1)*16 + li)) & 1u) ? pacc[f][r] : 0.f;
      Plds[lrow*72 + f*16 + li] = (short)f2bf(v);
    }
  }
  __syncthreads();
  {
    int row = tid>>2, sg = tid&3;
    const uint4* src = (const uint4*)&Plds[row*72 + sg*16];
    unsigned short* dst = Pbf + ((size_t)(b*NN + qt*64 + row))*NN + kt*64 + sg*16;
    uint4 v0 = src[0], v1 = *(const uint4*)((const short*)src + 8);
    *(uint4*)dst = v0;
    *(uint4*)(dst + 8) = v1;
  }
}

// ---- pass B: out = diag(1/(P*1)) P X — m97-structure LDS-staged GEMM ----
// BM=64, BN=128, BK=32. grid 768: b=bid&7 (XCD-affine: xT (1.5MB/batch) stays
// L2-resident; A-tiles shared by the 3 concurrent ct-blocks), mt=(bid>>3)&31,
// ct=bid>>8. 4 waves: wave (wr=w&1, wc=w>>1) owns 32 rows x 64 cols
// (acc 2x4 + 2 ones-rowsum MFMA). Per K-step: 12 global_load_lds(16B)
// (A 4 + B 8; wave w issues instrs w*3..w*3+2; LDS dest linear: lane l ->
// byte l*16 of each 1KB chunk) ; barrier ; 6x ds_read_b128 + 10 MFMA.
// 12 KB LDS -> 3 blocks/CU (12 waves), balanced 768 = 3*256.
__global__ __launch_bounds__(256, 3) void k_pv(const unsigned short* __restrict__ Pbf,
                                               const unsigned short* __restrict__ xTbf,
                                               float* __restrict__ out){
  __shared__ unsigned short Al[64*32];     // 4 KB
  __shared__ unsigned short Bl[128*32];    // 8 KB
  int tid = threadIdx.x;
  int w = tid>>6, l = tid&63, q = l>>4, li = l&15;
  int b  = blockIdx.x & 7;
  int mt = (blockIdx.x>>3) & 31;
  int ct = blockIdx.x >> 8;                // 0..2
  int m0 = mt*64;
  int d0 = ct*128;
  const unsigned short* Pb  = Pbf  + (size_t)b*NN*NN;
  const unsigned short* xTb = xTbf + (size_t)b*ND*NN;

  int wr = w & 1, wc = w >> 1;

  // staging assignment: instr id = w*3+j ; id<4 -> A chunk id ; else B chunk id-4
  int lr = l>>2, lk = (l&3)*8;             // lane -> row-in-chunk, k-elems
  const unsigned short* gsrc0; const unsigned short* gsrc1; const unsigned short* gsrc2;
  unsigned short* ldst0; unsigned short* ldst1; unsigned short* ldst2;
  {
    int id0 = w*3, id1 = w*3+1, id2 = w*3+2;
    ldst0 = (id0<4 ? Al + id0*512 : Bl + (id0-4)*512);
    ldst1 = (id1<4 ? Al + id1*512 : Bl + (id1-4)*512);
    ldst2 = (id2<4 ? Al + id2*512 : Bl + (id2-4)*512);
    gsrc0 = (id0<4 ? Pb + (size_t)(m0 + id0*16 + lr)*NN + lk
                   : xTb + (size_t)(d0 + (id0-4)*16 + lr)*NN + lk);
    gsrc1 = (id1<4 ? Pb + (size_t)(m0 + id1*16 + lr)*NN + lk
                   : xTb + (size_t)(d0 + (id1-4)*16 + lr)*NN + lk);
    gsrc2 = (id2<4 ? Pb + (size_t)(m0 + id2*16 + lr)*NN + lk
                   : xTb + (size_t)(d0 + (id2-4)*16 + lr)*NN + lk);
  }

  f32x4 acc[2][4];
  #pragma unroll
  for(int nc=0;nc<2;nc++)
    #pragma unroll
    for(int t=0;t<4;t++) acc[nc][t] = (f32x4)(0.f);
  f32x4 rs[2] = {(f32x4)(0.f),(f32x4)(0.f)};
  bf16x8 ones;
  #pragma unroll
  for(int i=0;i<8;i++) ones[i] = (short)0x3F80;   // bf16 1.0

  for(int k0=0; k0<NN; k0+=32){
    __syncthreads();                       // previous compute done (LDS reuse)
    gl2lds16(gsrc0 + k0, ldst0);
    gl2lds16(gsrc1 + k0, ldst1);
    gl2lds16(gsrc2 + k0, ldst2);
    __syncthreads();                       // staging visible (vmcnt drain)
    bf16x8 a0 = *(const bf16x8*)&Al[(wr*32 +      li)*32 + q*8];
    bf16x8 a1 = *(const bf16x8*)&Al[(wr*32 + 16 + li)*32 + q*8];
    bf16x8 bv[4];
    #pragma unroll
    for(int t=0;t<4;t++)
      bv[t] = *(const bf16x8*)&Bl[(wc*64 + t*16 + li)*32 + q*8];
    #pragma unroll
    for(int t=0;t<4;t++){
      acc[0][t] = __builtin_amdgcn_mfma_f32_16x16x32_bf16(a0, bv[t], acc[0][t], 0,0,0);
      acc[1][t] = __builtin_amdgcn_mfma_f32_16x16x32_bf16(a1, bv[t], acc[1][t], 0,0,0);
    }
    rs[0] = __builtin_amdgcn_mfma_f32_16x16x32_bf16(a0, ones, rs[0], 0,0,0);
    rs[1] = __builtin_amdgcn_mfma_f32_16x16x32_bf16(a1, ones, rs[1], 0,0,0);
  }

  #pragma unroll
  for(int nc=0;nc<2;nc++)
    #pragma unroll
    for(int r=0;r<4;r++){
      int row = m0 + wr*32 + nc*16 + q*4 + r;
      float inv = 1.f/(rs[nc][r] + 1e-8f);
      float* orow = out + ((size_t)(b*NN + row))*ND + d0 + wc*64;
      #pragma unroll
      for(int t=0;t<4;t++)
        orow[t*16 + li] = acc[nc][t][r] * inv;
    }
}

// ---- segout; block 0 also reduces the loss partials ----
__global__ void k_segout(const int* __restrict__ seg, float* __restrict__ o,
                         const float* __restrict__ klp, const float* __restrict__ mp,
                         float* __restrict__ outLoss){
  int tid = threadIdx.x;
  int i = blockIdx.x*256 + tid;
  o[i] = (float)seg[i];
  if(blockIdx.x==0){
    __shared__ float sa[4], sm[4];
    float a=0.f, m=0.f;
    for(int k=tid; k<NBLK_LOSS; k+=256){ a += klp[k]; m += mp[k]; }
    a = wsum(a); m = wsum(m);
    if((tid&63)==0){ sa[tid>>6]=a; sm[tid>>6]=m; }
    __syncthreads();
    if(tid==0)
      outLoss[0] = (sa[0]+sa[1]+sa[2]+sa[3])/((sm[0]+sm[1]+sm[2]+sm[3])+1e-8f);
  }
}

extern "C" void kernel_launch(void* const* d_in, const int* in_sizes, int n_in,
                              void* d_out, int out_size, void* d_ws, size_t ws_size,
                              hipStream_t stream) {
  const float* x      = (const float*)d_in[0];
  const int*   seg    = (const int*)d_in[1];
  const float* protos = (const float*)d_in[2];

  float* out     = (float*)d_out;                  // (B,N,D)
  float* outSeg  = out + OUT_ELEMS;                // (B,H,W)
  float* outLoss = outSeg + SEG_ELEMS;             // scalar
  float* outC    = outLoss + 1;                    // (B,N,R)

  // ws layout (~83 MB)
  unsigned short* xTbf = (unsigned short*)d_ws;            // 8*384*2048 bf16 (12.6MB)
  unsigned short* Kbf  = xTbf + (size_t)NB*ND*NN;          // 8*2048*64 bf16 (2MB)
  unsigned short* Pbf  = Kbf + (size_t)NB*NN*NR;           // 8*2048*2048 bf16 (64MB)
  float* kn      = (float*)(Pbf + (size_t)NB*NN*NN);       // 24576 f32
  float* maskp   = kn + NR*ND;                             // 16384  -- zero region start
  unsigned* prox = (unsigned*)(maskp + NB*NN);             // 8*2048*64 u32 (4MB) -- zero region end
  float* part    = (float*)(prox + (size_t)NB*NN*64);      // 8*32*64 (fully written)
  float* klp     = part + NB*32*64;                        // 4096 (fully written)
  float* mp      = klp + NBLK_LOSS;                        // 4096 (fully written)

  size_t zero_bytes = (size_t)NB*NN*4 + (size_t)NB*NN*64*4;   // maskp + prox
  hipMemsetAsync(maskp, 0, zero_bytes, stream);

  k_proto <<<dim3(NR),           dim3(64),  0, stream>>>(protos, kn);
  k_seg   <<<dim3(NB*65536/256), dim3(256), 0, stream>>>(seg, maskp, prox);
  k_csim  <<<dim3(NB*NN/64),     dim3(256), 0, stream>>>(x, kn, outC, xTbf, part);
  k_lossfc<<<dim3(NBLK_LOSS),    dim3(256), 0, stream>>>(outC, part, maskp, klp, mp, Kbf);
  k_qk    <<<dim3(8192),         dim3(256), 0, stream>>>(Kbf, prox, Pbf);
  k_pv    <<<dim3(768),          dim3(256), 0, stream>>>(Pbf, xTbf, out);
  k_segout<<<dim3(SEG_ELEMS/256),dim3(256), 0, stream>>>(seg, outSeg, klp, mp, outLoss);
}

// Round 5
// 272.606 us; speedup vs baseline: 1.3610x; 1.0692x over previous
//
#include <hip/hip_runtime.h>
#include <hip/hip_bf16.h>

// B=8, N=2048, D=384, R=64, H=W=256.
// Inputs:  x (B,N,D) f32, segments (B,H,W) i32, prototypes (1,R,D) f32.
// Outputs (f32, concat): out (B,N,D) | segments (B,H,W) | loss (1) | C (B,N,R)
//
// Pipeline (8 dispatches):
//   memset(maskp only, 64KB) ; k_proto ; k_seg (LDS-bitmask build, NO global
//   atomics: 64 blocks x (batch,node-range), prox fully written) ; k_csim
//   (S normalized + colsum partials + bf16 xT) ; k_lossfc (loss partials +
//   C + Kbf) ; k_qk (P=mask.*ChatChat^T bf16 -> ws) ; k_pv (out =
//   diag(1/(P*1)) P X — m97-structure LDS-staged GEMM) ; k_segout.
//
// k_seg history: global atomicOr version = 83.6us, WRITE_SIZE 65.6MB — 2.1M
// device-scope atomics each became a 32B fabric RMW (per-XCD L2s are not
// coherent; atomics execute at the coherence point). LDS atomics + full slab
// writeback eliminates all fabric RMW traffic.
#define NB 8
#define NN 2048
#define ND 384
#define NR 64
#define OUT_ELEMS (NB*NN*ND)        // 6291456
#define SEG_ELEMS (NB*256*256)      // 524288
#define NBLK_LOSS (NB*NN/4)         // 4096

typedef float  f32x4  __attribute__((ext_vector_type(4)));
typedef short  bf16x8 __attribute__((ext_vector_type(8)));

__device__ inline float wsum(float v){
  #pragma unroll
  for(int o=32;o;o>>=1) v += __shfl_xor(v,o,64);
  return v;
}
__device__ inline float wmax(float v){
  #pragma unroll
  for(int o=32;o;o>>=1) v = fmaxf(v,__shfl_xor(v,o,64));
  return v;
}
__device__ inline unsigned short f2bf(float f){
  unsigned u = __float_as_uint(f);
  return (unsigned short)((u + 0x8000u) >> 16);
}

// async global->LDS, 16 B per lane; LDS dest is wave-uniform base + lane*16
__device__ __forceinline__ void gl2lds16(const unsigned short* g, unsigned short* s){
  __builtin_amdgcn_global_load_lds(
      (const __attribute__((address_space(1))) unsigned int*)g,
      (__attribute__((address_space(3))) unsigned int*)s,
      16, 0, 0);
}

// ---- normalize prototypes -> kn (f32, unit rows) ----
__global__ void k_proto(const float* __restrict__ protos, float* __restrict__ kn){
  int r = blockIdx.x, l = threadIdx.x;
  float v[6]; float ss = 0.f;
  #pragma unroll
  for(int i=0;i<6;i++){ v[i] = protos[r*ND + l*6 + i]; ss += v[i]*v[i]; }
  ss = wsum(ss);
  float inv = 1.f / fmaxf(sqrtf(ss), 1e-8f);
  #pragma unroll
  for(int i=0;i<6;i++) kn[r*ND + l*6 + i] = v[i]*inv;
}

// ---- segments -> node mask + prox bitmask rows, built in LDS ----
// grid 64: b=bid>>3 (batch), rg=bid&7 (node range of 256). 1024 threads.
// LDS bitmask lm[256][64] (64KB) covers rows base..base+255 x 2048 bits.
// Pairs are inserted with LDS atomicOr (bank-parallel, no fabric RMW);
// the slab is then written to prox as a coalesced FULL write (so prox
// needs no memset). seg re-read 8x/batch = L2-resident 256KB.
__global__ __launch_bounds__(1024) void k_seg(const int* __restrict__ seg,
                                              float* __restrict__ mask,
                                              unsigned* __restrict__ prox){
  __shared__ unsigned lm[256*64];   // 64 KB
  int tid = threadIdx.x;
  int b  = blockIdx.x >> 3;
  int rg = blockIdx.x & 7;
  int base = rg << 8;
  for(int i=tid; i<256*64; i+=1024) lm[i] = 0u;
  __syncthreads();
  const int* sb = seg + b*65536;
  for(int p = tid; p < 65536; p += 1024){
    int i = p >> 8, j = p & 255;
    int s = sb[p];
    if((s>>8)==rg) mask[(b<<11) + s] = 1.f;
    if(j < 255){
      int s2 = sb[p+1];
      if(s != s2 && s != 0 && s2 != 0){
        if((s >>8)==rg) atomicOr(&lm[((s -base)<<6) + (s2>>5)], 1u<<(s2&31));
        if((s2>>8)==rg) atomicOr(&lm[((s2-base)<<6) + (s >>5)], 1u<<(s &31));
      }
    }
    if(i < 255){
      int s2 = sb[p+256];
      if(s != s2 && s != 0 && s2 != 0){
        if((s >>8)==rg) atomicOr(&lm[((s -base)<<6) + (s2>>5)], 1u<<(s2&31));
        if((s2>>8)==rg) atomicOr(&lm[((s2-base)<<6) + (s >>5)], 1u<<(s &31));
      }
    }
  }
  __syncthreads();
  // coalesced full writeback of the 64KB slab
  unsigned* dst = prox + ((size_t)(b<<11) + base)*64;
  for(int i=tid; i<256*64/4; i+=1024)
    *(uint4*)(dst + i*4) = *(const uint4*)&lm[i*4];
}

// ---- Csim GEMM: writes NORMALIZED s, colsum partials, bf16 xT ----
__global__ __launch_bounds__(256) void k_csim(const float* __restrict__ x,
                                              const float* __restrict__ kn,
                                              float* __restrict__ Sout,
                                              unsigned short* __restrict__ xTbf,
                                              float* __restrict__ part){
  __shared__ float xT[32*68];
  __shared__ float kT[32*68];
  __shared__ float xinvS[64];
  __shared__ float csh[16*64];
  int t = threadIdx.x;
  int m0 = blockIdx.x * 64;
  float acc[4][4] = {};
  int mload = t>>2, koff = (t&3)*8;
  int mb = (t>>4)*4, rb = (t&15)*4;
  float ssq = 0.f;
  for(int c=0;c<12;c++){
    int k0 = c*32;
    __syncthreads();
    const float4* xg = (const float4*)(x + (size_t)(m0+mload)*ND + k0 + koff);
    float4 a = xg[0], bq = xg[1];
    ssq += a.x*a.x + a.y*a.y + a.z*a.z + a.w*a.w
         + bq.x*bq.x + bq.y*bq.y + bq.z*bq.z + bq.w*bq.w;
    xT[(koff+0)*68+mload]=a.x;  xT[(koff+1)*68+mload]=a.y;  xT[(koff+2)*68+mload]=a.z;  xT[(koff+3)*68+mload]=a.w;
    xT[(koff+4)*68+mload]=bq.x; xT[(koff+5)*68+mload]=bq.y; xT[(koff+6)*68+mload]=bq.z; xT[(koff+7)*68+mload]=bq.w;
    const float4* kg = (const float4*)(kn + mload*ND + k0 + koff);
    float4 ka = kg[0], kb = kg[1];
    kT[(koff+0)*68+mload]=ka.x; kT[(koff+1)*68+mload]=ka.y; kT[(koff+2)*68+mload]=ka.z; kT[(koff+3)*68+mload]=ka.w;
    kT[(koff+4)*68+mload]=kb.x; kT[(koff+5)*68+mload]=kb.y; kT[(koff+6)*68+mload]=kb.z; kT[(koff+7)*68+mload]=kb.w;
    __syncthreads();
    {
      int k2 = t>>3, mo = (t&7)*8;
      const float* src = &xT[k2*68 + mo];
      float4 aa = *(const float4*)src;
      float4 bb = *(const float4*)(src+4);
      uint4 o;
      o.x = (unsigned)f2bf(aa.x) | ((unsigned)f2bf(aa.y)<<16);
      o.y = (unsigned)f2bf(aa.z) | ((unsigned)f2bf(aa.w)<<16);
      o.z = (unsigned)f2bf(bb.x) | ((unsigned)f2bf(bb.y)<<16);
      o.w = (unsigned)f2bf(bb.z) | ((unsigned)f2bf(bb.w)<<16);
      int bb2 = m0 >> 11, ml = m0 & 2047;
      *(uint4*)(xTbf + ((size_t)(bb2*ND + k0 + k2))*NN + ml + mo) = o;
    }
    for(int k=0;k<32;k++){
      float xv[4], kv[4];
      *(float4*)xv = *(const float4*)&xT[k*68+mb];
      *(float4*)kv = *(const float4*)&kT[k*68+rb];
      #pragma unroll
      for(int mi=0;mi<4;mi++)
        #pragma unroll
        for(int ri=0;ri<4;ri++) acc[mi][ri] += xv[mi]*kv[ri];
    }
  }
  ssq += __shfl_xor(ssq,1,64);
  ssq += __shfl_xor(ssq,2,64);
  if((t&3)==0) xinvS[mload] = 1.f / fmaxf(sqrtf(ssq), 1e-8f);
  __syncthreads();
  // epilogue: raw -> row-normalized s (rowsum over the 16-lane rb group)
  float sv[4][4];
  #pragma unroll
  for(int mi=0;mi<4;mi++){
    float xin = xinvS[mb+mi];
    float rsum = 0.f;
    #pragma unroll
    for(int ri=0;ri<4;ri++){
      float vv = (acc[mi][ri]*xin + 1.f)*0.5f;
      sv[mi][ri] = vv; rsum += vv;
    }
    rsum += __shfl_xor(rsum,1,64);
    rsum += __shfl_xor(rsum,2,64);
    rsum += __shfl_xor(rsum,4,64);
    rsum += __shfl_xor(rsum,8,64);
    float inv = 1.f/rsum;
    #pragma unroll
    for(int ri=0;ri<4;ri++) sv[mi][ri] *= inv;
    *(float4*)&Sout[(size_t)(m0+mb+mi)*NR + rb] = *(const float4*)sv[mi];
  }
  // colsum partial for this block's 64 nodes (no atomics: fully-written array)
  {
    float4 pc;
    pc.x = sv[0][0]+sv[1][0]+sv[2][0]+sv[3][0];
    pc.y = sv[0][1]+sv[1][1]+sv[2][1]+sv[3][1];
    pc.z = sv[0][2]+sv[1][2]+sv[2][2]+sv[3][2];
    pc.w = sv[0][3]+sv[1][3]+sv[2][3]+sv[3][3];
    *(float4*)&csh[(t>>4)*64 + rb] = pc;
  }
  __syncthreads();
  if(t < 64){
    float a = 0.f;
    #pragma unroll
    for(int g=0;g<16;g++) a += csh[g*64 + t];
    part[(size_t)blockIdx.x*64 + t] = a;        // part[b*32+chunk][r]
  }
}

// ---- DEC KL loss (partial stores) + C=softmax(s) in place + Kbf ----
__global__ void k_lossfc(float* Smat, const float* __restrict__ part,
                         const float* __restrict__ mask,
                         float* __restrict__ klp, float* __restrict__ mp,
                         unsigned short* __restrict__ Kbf){
  __shared__ float shk[4], shm[4];
  int w = threadIdx.x>>6, l = threadIdx.x&63;
  int node = blockIdx.x*4 + w;
  int b = node >> 11;
  float s = Smat[(size_t)node*NR + l];
  float csm = 0.f;
  #pragma unroll
  for(int c=0;c<32;c++) csm += part[(size_t)((b<<5)+c)*64 + l];
  float p = s*s/(csm + 1e-8f);
  float ps = wsum(p);
  float P = p/(ps + 1e-8f);
  float term = P*(logf(P + 1e-8f) - logf(s + 1e-8f));
  float kl = wsum(term);
  if(l==0){ float mv = mask[node]; shk[w] = kl*mv; shm[w] = mv; }
  float mx = wmax(s);
  float e = expf(s - mx);
  float Z = wsum(e);
  float c = e / Z;
  float cn2 = wsum(c*c);
  Smat[(size_t)node*NR + l] = c;
  Kbf[(size_t)node*NR + l] = f2bf(c * rsqrtf(cn2));
  __syncthreads();
  if(threadIdx.x==0){
    klp[blockIdx.x] = shk[0]+shk[1]+shk[2]+shk[3];
    mp [blockIdx.x] = shm[0]+shm[1]+shm[2]+shm[3];
  }
}

// ---- pass A: P tile (64x64) = mask .* (Chat Chat^T), bf16 -> ws ----
// grid 8192: b=bid&7, qt=(bid>>3)&31, kt=bid>>8. One barrier per block.
__global__ __launch_bounds__(256) void k_qk(const unsigned short* __restrict__ Kbf,
                                            const unsigned* __restrict__ prox,
                                            unsigned short* __restrict__ Pbf){
  __shared__ short Plds[64*72];
  int tid = threadIdx.x;
  int w = tid>>6, l = tid&63, q = l>>4, li = l&15;
  int b  = blockIdx.x & 7;
  int qt = (blockIdx.x>>3) & 31;
  int kt = blockIdx.x >> 8;
  const unsigned short* Kb = Kbf + (size_t)b*NN*NR;

  int arow = qt*64 + w*16 + li;
  bf16x8 af[2];
  af[0] = *(const bf16x8*)(Kb + (size_t)arow*NR + q*8);
  af[1] = *(const bf16x8*)(Kb + (size_t)arow*NR + 32 + q*8);
  f32x4 pacc[4] = {(f32x4)(0.f),(f32x4)(0.f),(f32x4)(0.f),(f32x4)(0.f)};
  #pragma unroll
  for(int f=0;f<4;f++){
    int brow = kt*64 + f*16 + li;
    bf16x8 b0 = *(const bf16x8*)(Kb + (size_t)brow*NR + q*8);
    bf16x8 b1 = *(const bf16x8*)(Kb + (size_t)brow*NR + 32 + q*8);
    pacc[f] = __builtin_amdgcn_mfma_f32_16x16x32_bf16(af[0], b0, pacc[f], 0,0,0);
    pacc[f] = __builtin_amdgcn_mfma_f32_16x16x32_bf16(af[1], b1, pacc[f], 0,0,0);
  }
  #pragma unroll
  for(int r=0;r<4;r++){
    int lrow = w*16 + q*4 + r;
    int grow = qt*64 + lrow;
    uint2 mw = *(const uint2*)(prox + ((size_t)(b*NN + grow))*64 + kt*2);
    if(qt==kt){
      if((lrow>>5)==0) mw.x |= 1u<<(lrow&31); else mw.y |= 1u<<(lrow&31);
    }
    #pragma unroll
    for(int f=0;f<4;f++){
      unsigned wd = (f<2) ? mw.x : mw.y;
      float v = ((wd >> ((f&1)*16 + li)) & 1u) ? pacc[f][r] : 0.f;
      Plds[lrow*72 + f*16 + li] = (short)f2bf(v);
    }
  }
  __syncthreads();
  {
    int row = tid>>2, sg = tid&3;
    const uint4* src = (const uint4*)&Plds[row*72 + sg*16];
    unsigned short* dst = Pbf + ((size_t)(b*NN + qt*64 + row))*NN + kt*64 + sg*16;
    uint4 v0 = src[0], v1 = *(const uint4*)((const short*)src + 8);
    *(uint4*)dst = v0;
    *(uint4*)(dst + 8) = v1;
  }
}

// ---- pass B: out = diag(1/(P*1)) P X — m97-structure LDS-staged GEMM ----
// BM=64, BN=128, BK=32. grid 768: b=bid&7, mt=(bid>>3)&31, ct=bid>>8.
// 4 waves: wave (wr=w&1, wc=w>>1) owns 32 rows x 64 cols. Per K-step:
// 12 global_load_lds(16B) ; barrier ; 6x ds_read_b128 + 10 MFMA.
// 12 KB LDS -> 3 blocks/CU (12 waves), balanced 768 = 3*256.
__global__ __launch_bounds__(256, 3) void k_pv(const unsigned short* __restrict__ Pbf,
                                               const unsigned short* __restrict__ xTbf,
                                               float* __restrict__ out){
  __shared__ unsigned short Al[64*32];     // 4 KB
  __shared__ unsigned short Bl[128*32];    // 8 KB
  int tid = threadIdx.x;
  int w = tid>>6, l = tid&63, q = l>>4, li = l&15;
  int b  = blockIdx.x & 7;
  int mt = (blockIdx.x>>3) & 31;
  int ct = blockIdx.x >> 8;                // 0..2
  int m0 = mt*64;
  int d0 = ct*128;
  const unsigned short* Pb  = Pbf  + (size_t)b*NN*NN;
  const unsigned short* xTb = xTbf + (size_t)b*ND*NN;

  int wr = w & 1, wc = w >> 1;

  // staging assignment: instr id = w*3+j ; id<4 -> A chunk id ; else B chunk id-4
  int lr = l>>2, lk = (l&3)*8;             // lane -> row-in-chunk, k-elems
  const unsigned short* gsrc0; const unsigned short* gsrc1; const unsigned short* gsrc2;
  unsigned short* ldst0; unsigned short* ldst1; unsigned short* ldst2;
  {
    int id0 = w*3, id1 = w*3+1, id2 = w*3+2;
    ldst0 = (id0<4 ? Al + id0*512 : Bl + (id0-4)*512);
    ldst1 = (id1<4 ? Al + id1*512 : Bl + (id1-4)*512);
    ldst2 = (id2<4 ? Al + id2*512 : Bl + (id2-4)*512);
    gsrc0 = (id0<4 ? Pb + (size_t)(m0 + id0*16 + lr)*NN + lk
                   : xTb + (size_t)(d0 + (id0-4)*16 + lr)*NN + lk);
    gsrc1 = (id1<4 ? Pb + (size_t)(m0 + id1*16 + lr)*NN + lk
                   : xTb + (size_t)(d0 + (id1-4)*16 + lr)*NN + lk);
    gsrc2 = (id2<4 ? Pb + (size_t)(m0 + id2*16 + lr)*NN + lk
                   : xTb + (size_t)(d0 + (id2-4)*16 + lr)*NN + lk);
  }

  f32x4 acc[2][4];
  #pragma unroll
  for(int nc=0;nc<2;nc++)
    #pragma unroll
    for(int t=0;t<4;t++) acc[nc][t] = (f32x4)(0.f);
  f32x4 rs[2] = {(f32x4)(0.f),(f32x4)(0.f)};
  bf16x8 ones;
  #pragma unroll
  for(int i=0;i<8;i++) ones[i] = (short)0x3F80;   // bf16 1.0

  for(int k0=0; k0<NN; k0+=32){
    __syncthreads();                       // previous compute done (LDS reuse)
    gl2lds16(gsrc0 + k0, ldst0);
    gl2lds16(gsrc1 + k0, ldst1);
    gl2lds16(gsrc2 + k0, ldst2);
    __syncthreads();                       // staging visible (vmcnt drain)
    bf16x8 a0 = *(const bf16x8*)&Al[(wr*32 +      li)*32 + q*8];
    bf16x8 a1 = *(const bf16x8*)&Al[(wr*32 + 16 + li)*32 + q*8];
    bf16x8 bv[4];
    #pragma unroll
    for(int t=0;t<4;t++)
      bv[t] = *(const bf16x8*)&Bl[(wc*64 + t*16 + li)*32 + q*8];
    #pragma unroll
    for(int t=0;t<4;t++){
      acc[0][t] = __builtin_amdgcn_mfma_f32_16x16x32_bf16(a0, bv[t], acc[0][t], 0,0,0);
      acc[1][t] = __builtin_amdgcn_mfma_f32_16x16x32_bf16(a1, bv[t], acc[1][t], 0,0,0);
    }
    rs[0] = __builtin_amdgcn_mfma_f32_16x16x32_bf16(a0, ones, rs[0], 0,0,0);
    rs[1] = __builtin_amdgcn_mfma_f32_16x16x32_bf16(a1, ones, rs[1], 0,0,0);
  }

  #pragma unroll
  for(int nc=0;nc<2;nc++)
    #pragma unroll
    for(int r=0;r<4;r++){
      int row = m0 + wr*32 + nc*16 + q*4 + r;
      float inv = 1.f/(rs[nc][r] + 1e-8f);
      float* orow = out + ((size_t)(b*NN + row))*ND + d0 + wc*64;
      #pragma unroll
      for(int t=0;t<4;t++)
        orow[t*16 + li] = acc[nc][t][r] * inv;
    }
}

// ---- segout; block 0 also reduces the loss partials ----
__global__ void k_segout(const int* __restrict__ seg, float* __restrict__ o,
                         const float* __restrict__ klp, const float* __restrict__ mp,
                         float* __restrict__ outLoss){
  int tid = threadIdx.x;
  int i = blockIdx.x*256 + tid;
  o[i] = (float)seg[i];
  if(blockIdx.x==0){
    __shared__ float sa[4], sm[4];
    float a=0.f, m=0.f;
    for(int k=tid; k<NBLK_LOSS; k+=256){ a += klp[k]; m += mp[k]; }
    a = wsum(a); m = wsum(m);
    if((tid&63)==0){ sa[tid>>6]=a; sm[tid>>6]=m; }
    __syncthreads();
    if(tid==0)
      outLoss[0] = (sa[0]+sa[1]+sa[2]+sa[3])/((sm[0]+sm[1]+sm[2]+sm[3])+1e-8f);
  }
}

extern "C" void kernel_launch(void* const* d_in, const int* in_sizes, int n_in,
                              void* d_out, int out_size, void* d_ws, size_t ws_size,
                              hipStream_t stream) {
  const float* x      = (const float*)d_in[0];
  const int*   seg    = (const int*)d_in[1];
  const float* protos = (const float*)d_in[2];

  float* out     = (float*)d_out;                  // (B,N,D)
  float* outSeg  = out + OUT_ELEMS;                // (B,H,W)
  float* outLoss = outSeg + SEG_ELEMS;             // scalar
  float* outC    = outLoss + 1;                    // (B,N,R)

  // ws layout (~83 MB)
  unsigned short* xTbf = (unsigned short*)d_ws;            // 8*384*2048 bf16 (12.6MB)
  unsigned short* Kbf  = xTbf + (size_t)NB*ND*NN;          // 8*2048*64 bf16 (2MB)
  unsigned short* Pbf  = Kbf + (size_t)NB*NN*NR;           // 8*2048*2048 bf16 (64MB)
  float* kn      = (float*)(Pbf + (size_t)NB*NN*NN);       // 24576 f32
  float* maskp   = kn + NR*ND;                             // 16384  -- zero region (64KB)
  unsigned* prox = (unsigned*)(maskp + NB*NN);             // 8*2048*64 u32 (4MB, fully written by k_seg)
  float* part    = (float*)(prox + (size_t)NB*NN*64);      // 8*32*64 (fully written)
  float* klp     = part + NB*32*64;                        // 4096 (fully written)
  float* mp      = klp + NBLK_LOSS;                        // 4096 (fully written)

  // only maskp needs zeroing now (prox is fully written by k_seg)
  hipMemsetAsync(maskp, 0, (size_t)NB*NN*4, stream);

  k_proto <<<dim3(NR),           dim3(64),   0, stream>>>(protos, kn);
  k_seg   <<<dim3(64),           dim3(1024), 0, stream>>>(seg, maskp, prox);
  k_csim  <<<dim3(NB*NN/64),     dim3(256),  0, stream>>>(x, kn, outC, xTbf, part);
  k_lossfc<<<dim3(NBLK_LOSS),    dim3(256),  0, stream>>>(outC, part, maskp, klp, mp, Kbf);
  k_qk    <<<dim3(8192),         dim3(256),  0, stream>>>(Kbf, prox, Pbf);
  k_pv    <<<dim3(768),          dim3(256),  0, stream>>>(Pbf, xTbf, out);
  k_segout<<<dim3(SEG_ELEMS/256),dim3(256),  0, stream>>>(seg, outSeg, klp, mp, outLoss);
}

// Round 6
// 231.140 us; speedup vs baseline: 1.6052x; 1.1794x over previous
//
#include <hip/hip_runtime.h>
#include <hip/hip_bf16.h>

// B=8, N=2048, D=384, R=64, H=W=256.
// Inputs:  x (B,N,D) f32, segments (B,H,W) i32, prototypes (1,R,D) f32.
// Outputs (f32, concat): out (B,N,D) | segments (B,H,W) | loss (1) | C (B,N,R)
//
// Pipeline (8 dispatches):
//   memset(maskp only, 64KB) ; k_proto ; k_seg (LDS-bitmask build, 256 blocks
//   x (batch, 64-node range), int4 pixel loads, NO global atomics, prox fully
//   written) ; k_csim (S normalized + colsum partials + bf16 xT) ; k_lossfc
//   (loss partials + C + Kbf) ; k_qk (P=mask.*ChatChat^T bf16 -> ws) ; k_pv
//   (out = diag(1/(P*1)) P X — m97-structure LDS-staged GEMM) ; k_segout.
//
// k_seg history: global atomicOr = 83.6us (65MB fabric RMW). LDS-bitmask v1
// (64 blocks x 64KB LDS) = 76.7us — traffic fixed (WRITE 4MB) but
// occupancy 10%: 192/256 CUs idle + 64 serial scalar iters. v2 (this):
// 32 ranges x 16KB LDS -> 256 blocks, int4 loads, 16 iters.
#define NB 8
#define NN 2048
#define ND 384
#define NR 64
#define OUT_ELEMS (NB*NN*ND)        // 6291456
#define SEG_ELEMS (NB*256*256)      // 524288
#define NBLK_LOSS (NB*NN/4)         // 4096

typedef float  f32x4  __attribute__((ext_vector_type(4)));
typedef short  bf16x8 __attribute__((ext_vector_type(8)));

__device__ inline float wsum(float v){
  #pragma unroll
  for(int o=32;o;o>>=1) v += __shfl_xor(v,o,64);
  return v;
}
__device__ inline float wmax(float v){
  #pragma unroll
  for(int o=32;o;o>>=1) v = fmaxf(v,__shfl_xor(v,o,64));
  return v;
}
__device__ inline unsigned short f2bf(float f){
  unsigned u = __float_as_uint(f);
  return (unsigned short)((u + 0x8000u) >> 16);
}

// async global->LDS, 16 B per lane; LDS dest is wave-uniform base + lane*16
__device__ __forceinline__ void gl2lds16(const unsigned short* g, unsigned short* s){
  __builtin_amdgcn_global_load_lds(
      (const __attribute__((address_space(1))) unsigned int*)g,
      (__attribute__((address_space(3))) unsigned int*)s,
      16, 0, 0);
}

// ---- normalize prototypes -> kn (f32, unit rows) ----
__global__ void k_proto(const float* __restrict__ protos, float* __restrict__ kn){
  int r = blockIdx.x, l = threadIdx.x;
  float v[6]; float ss = 0.f;
  #pragma unroll
  for(int i=0;i<6;i++){ v[i] = protos[r*ND + l*6 + i]; ss += v[i]*v[i]; }
  ss = wsum(ss);
  float inv = 1.f / fmaxf(sqrtf(ss), 1e-8f);
  #pragma unroll
  for(int i=0;i<6;i++) kn[r*ND + l*6 + i] = v[i]*inv;
}

// ---- segments -> node mask + prox bitmask rows, built in LDS ----
// grid 256: b=bid&7 (batch), rg=bid>>3 (64-node range). 1024 threads.
// LDS bitmask lm[64][64] u32 (16KB) = rows base..base+63 x 2048 bits.
// Each thread: 16 iters x int4 (4 pixels) + scalar next + int4 row below.
// Pairs inserted via LDS atomicOr (range-filtered ~1/32); slab written back
// as one coalesced uint4/thread (prox fully written -> no memset).
__global__ __launch_bounds__(1024) void k_seg(const int* __restrict__ seg,
                                              float* __restrict__ mask,
                                              unsigned* __restrict__ prox){
  __shared__ unsigned lm[64*64];    // 16 KB
  int tid = threadIdx.x;
  int b  = blockIdx.x & 7;
  int rg = blockIdx.x >> 3;         // 0..31
  int base = rg << 6;
  for(int i=tid; i<64*64; i+=1024) lm[i] = 0u;
  __syncthreads();
  const int* sb = seg + b*65536;

#define PAIR(S, S2) { \
    if((S) != (S2) && (S) != 0 && (S2) != 0){ \
      if(((S )>>6)==rg) atomicOr(&lm[(((S )&63)<<6) + ((S2)>>5)], 1u<<((S2)&31)); \
      if(((S2)>>6)==rg) atomicOr(&lm[(((S2)&63)<<6) + ((S )>>5)], 1u<<((S )&31)); \
    } }

  #pragma unroll 1
  for(int it=0; it<16; ++it){
    int g = it*1024 + tid;          // int4 group index in [0,16384)
    int p = g*4;
    int i = g >> 6;                 // row 0..255
    int j = (g & 63)*4;             // col 0,4,...,252
    int4 a = *(const int4*)(sb + p);
    // node-presence mask: exactly one range claims each pixel
    if((a.x>>6)==rg) mask[(b<<11) + a.x] = 1.f;
    if((a.y>>6)==rg) mask[(b<<11) + a.y] = 1.f;
    if((a.z>>6)==rg) mask[(b<<11) + a.z] = 1.f;
    if((a.w>>6)==rg) mask[(b<<11) + a.w] = 1.f;
    // horizontal pairs within the int4
    PAIR(a.x, a.y); PAIR(a.y, a.z); PAIR(a.z, a.w);
    // horizontal cross-group pair (j+3, j+4)
    if(j < 252){
      int n = sb[p + 4];
      PAIR(a.w, n);
    }
    // vertical pairs with the row below
    if(i < 255){
      int4 v = *(const int4*)(sb + p + 256);
      PAIR(a.x, v.x); PAIR(a.y, v.y); PAIR(a.z, v.z); PAIR(a.w, v.w);
    }
  }
#undef PAIR
  __syncthreads();
  // coalesced full writeback of the 16KB slab (one uint4 per thread)
  unsigned* dst = prox + ((size_t)(b<<11) + base)*64;
  *(uint4*)(dst + tid*4) = *(const uint4*)&lm[tid*4];
}

// ---- Csim GEMM: writes NORMALIZED s, colsum partials, bf16 xT ----
__global__ __launch_bounds__(256) void k_csim(const float* __restrict__ x,
                                              const float* __restrict__ kn,
                                              float* __restrict__ Sout,
                                              unsigned short* __restrict__ xTbf,
                                              float* __restrict__ part){
  __shared__ float xT[32*68];
  __shared__ float kT[32*68];
  __shared__ float xinvS[64];
  __shared__ float csh[16*64];
  int t = threadIdx.x;
  int m0 = blockIdx.x * 64;
  float acc[4][4] = {};
  int mload = t>>2, koff = (t&3)*8;
  int mb = (t>>4)*4, rb = (t&15)*4;
  float ssq = 0.f;
  for(int c=0;c<12;c++){
    int k0 = c*32;
    __syncthreads();
    const float4* xg = (const float4*)(x + (size_t)(m0+mload)*ND + k0 + koff);
    float4 a = xg[0], bq = xg[1];
    ssq += a.x*a.x + a.y*a.y + a.z*a.z + a.w*a.w
         + bq.x*bq.x + bq.y*bq.y + bq.z*bq.z + bq.w*bq.w;
    xT[(koff+0)*68+mload]=a.x;  xT[(koff+1)*68+mload]=a.y;  xT[(koff+2)*68+mload]=a.z;  xT[(koff+3)*68+mload]=a.w;
    xT[(koff+4)*68+mload]=bq.x; xT[(koff+5)*68+mload]=bq.y; xT[(koff+6)*68+mload]=bq.z; xT[(koff+7)*68+mload]=bq.w;
    const float4* kg = (const float4*)(kn + mload*ND + k0 + koff);
    float4 ka = kg[0], kb = kg[1];
    kT[(koff+0)*68+mload]=ka.x; kT[(koff+1)*68+mload]=ka.y; kT[(koff+2)*68+mload]=ka.z; kT[(koff+3)*68+mload]=ka.w;
    kT[(koff+4)*68+mload]=kb.x; kT[(koff+5)*68+mload]=kb.y; kT[(koff+6)*68+mload]=kb.z; kT[(koff+7)*68+mload]=kb.w;
    __syncthreads();
    {
      int k2 = t>>3, mo = (t&7)*8;
      const float* src = &xT[k2*68 + mo];
      float4 aa = *(const float4*)src;
      float4 bb = *(const float4*)(src+4);
      uint4 o;
      o.x = (unsigned)f2bf(aa.x) | ((unsigned)f2bf(aa.y)<<16);
      o.y = (unsigned)f2bf(aa.z) | ((unsigned)f2bf(aa.w)<<16);
      o.z = (unsigned)f2bf(bb.x) | ((unsigned)f2bf(bb.y)<<16);
      o.w = (unsigned)f2bf(bb.z) | ((unsigned)f2bf(bb.w)<<16);
      int bb2 = m0 >> 11, ml = m0 & 2047;
      *(uint4*)(xTbf + ((size_t)(bb2*ND + k0 + k2))*NN + ml + mo) = o;
    }
    for(int k=0;k<32;k++){
      float xv[4], kv[4];
      *(float4*)xv = *(const float4*)&xT[k*68+mb];
      *(float4*)kv = *(const float4*)&kT[k*68+rb];
      #pragma unroll
      for(int mi=0;mi<4;mi++)
        #pragma unroll
        for(int ri=0;ri<4;ri++) acc[mi][ri] += xv[mi]*kv[ri];
    }
  }
  ssq += __shfl_xor(ssq,1,64);
  ssq += __shfl_xor(ssq,2,64);
  if((t&3)==0) xinvS[mload] = 1.f / fmaxf(sqrtf(ssq), 1e-8f);
  __syncthreads();
  // epilogue: raw -> row-normalized s (rowsum over the 16-lane rb group)
  float sv[4][4];
  #pragma unroll
  for(int mi=0;mi<4;mi++){
    float xin = xinvS[mb+mi];
    float rsum = 0.f;
    #pragma unroll
    for(int ri=0;ri<4;ri++){
      float vv = (acc[mi][ri]*xin + 1.f)*0.5f;
      sv[mi][ri] = vv; rsum += vv;
    }
    rsum += __shfl_xor(rsum,1,64);
    rsum += __shfl_xor(rsum,2,64);
    rsum += __shfl_xor(rsum,4,64);
    rsum += __shfl_xor(rsum,8,64);
    float inv = 1.f/rsum;
    #pragma unroll
    for(int ri=0;ri<4;ri++) sv[mi][ri] *= inv;
    *(float4*)&Sout[(size_t)(m0+mb+mi)*NR + rb] = *(const float4*)sv[mi];
  }
  // colsum partial for this block's 64 nodes (no atomics: fully-written array)
  {
    float4 pc;
    pc.x = sv[0][0]+sv[1][0]+sv[2][0]+sv[3][0];
    pc.y = sv[0][1]+sv[1][1]+sv[2][1]+sv[3][1];
    pc.z = sv[0][2]+sv[1][2]+sv[2][2]+sv[3][2];
    pc.w = sv[0][3]+sv[1][3]+sv[2][3]+sv[3][3];
    *(float4*)&csh[(t>>4)*64 + rb] = pc;
  }
  __syncthreads();
  if(t < 64){
    float a = 0.f;
    #pragma unroll
    for(int g=0;g<16;g++) a += csh[g*64 + t];
    part[(size_t)blockIdx.x*64 + t] = a;        // part[b*32+chunk][r]
  }
}

// ---- DEC KL loss (partial stores) + C=softmax(s) in place + Kbf ----
__global__ void k_lossfc(float* Smat, const float* __restrict__ part,
                         const float* __restrict__ mask,
                         float* __restrict__ klp, float* __restrict__ mp,
                         unsigned short* __restrict__ Kbf){
  __shared__ float shk[4], shm[4];
  int w = threadIdx.x>>6, l = threadIdx.x&63;
  int node = blockIdx.x*4 + w;
  int b = node >> 11;
  float s = Smat[(size_t)node*NR + l];
  float csm = 0.f;
  #pragma unroll
  for(int c=0;c<32;c++) csm += part[(size_t)((b<<5)+c)*64 + l];
  float p = s*s/(csm + 1e-8f);
  float ps = wsum(p);
  float P = p/(ps + 1e-8f);
  float term = P*(logf(P + 1e-8f) - logf(s + 1e-8f));
  float kl = wsum(term);
  if(l==0){ float mv = mask[node]; shk[w] = kl*mv; shm[w] = mv; }
  float mx = wmax(s);
  float e = expf(s - mx);
  float Z = wsum(e);
  float c = e / Z;
  float cn2 = wsum(c*c);
  Smat[(size_t)node*NR + l] = c;
  Kbf[(size_t)node*NR + l] = f2bf(c * rsqrtf(cn2));
  __syncthreads();
  if(threadIdx.x==0){
    klp[blockIdx.x] = shk[0]+shk[1]+shk[2]+shk[3];
    mp [blockIdx.x] = shm[0]+shm[1]+shm[2]+shm[3];
  }
}

// ---- pass A: P tile (64x64) = mask .* (Chat Chat^T), bf16 -> ws ----
// grid 8192: b=bid&7, qt=(bid>>3)&31, kt=bid>>8. One barrier per block.
__global__ __launch_bounds__(256) void k_qk(const unsigned short* __restrict__ Kbf,
                                            const unsigned* __restrict__ prox,
                                            unsigned short* __restrict__ Pbf){
  __shared__ short Plds[64*72];
  int tid = threadIdx.x;
  int w = tid>>6, l = tid&63, q = l>>4, li = l&15;
  int b  = blockIdx.x & 7;
  int qt = (blockIdx.x>>3) & 31;
  int kt = blockIdx.x >> 8;
  const unsigned short* Kb = Kbf + (size_t)b*NN*NR;

  int arow = qt*64 + w*16 + li;
  bf16x8 af[2];
  af[0] = *(const bf16x8*)(Kb + (size_t)arow*NR + q*8);
  af[1] = *(const bf16x8*)(Kb + (size_t)arow*NR + 32 + q*8);
  f32x4 pacc[4] = {(f32x4)(0.f),(f32x4)(0.f),(f32x4)(0.f),(f32x4)(0.f)};
  #pragma unroll
  for(int f=0;f<4;f++){
    int brow = kt*64 + f*16 + li;
    bf16x8 b0 = *(const bf16x8*)(Kb + (size_t)brow*NR + q*8);
    bf16x8 b1 = *(const bf16x8*)(Kb + (size_t)brow*NR + 32 + q*8);
    pacc[f] = __builtin_amdgcn_mfma_f32_16x16x32_bf16(af[0], b0, pacc[f], 0,0,0);
    pacc[f] = __builtin_amdgcn_mfma_f32_16x16x32_bf16(af[1], b1, pacc[f], 0,0,0);
  }
  #pragma unroll
  for(int r=0;r<4;r++){
    int lrow = w*16 + q*4 + r;
    int grow = qt*64 + lrow;
    uint2 mw = *(const uint2*)(prox + ((size_t)(b*NN + grow))*64 + kt*2);
    if(qt==kt){
      if((lrow>>5)==0) mw.x |= 1u<<(lrow&31); else mw.y |= 1u<<(lrow&31);
    }
    #pragma unroll
    for(int f=0;f<4;f++){
      unsigned wd = (f<2) ? mw.x : mw.y;
      float v = ((wd >> ((f&1)*16 + li)) & 1u) ? pacc[f][r] : 0.f;
      Plds[lrow*72 + f*16 + li] = (short)f2bf(v);
    }
  }
  __syncthreads();
  {
    int row = tid>>2, sg = tid&3;
    const uint4* src = (const uint4*)&Plds[row*72 + sg*16];
    unsigned short* dst = Pbf + ((size_t)(b*NN + qt*64 + row))*NN + kt*64 + sg*16;
    uint4 v0 = src[0], v1 = *(const uint4*)((const short*)src + 8);
    *(uint4*)dst = v0;
    *(uint4*)(dst + 8) = v1;
  }
}

// ---- pass B: out = diag(1/(P*1)) P X — m97-structure LDS-staged GEMM ----
// BM=64, BN=128, BK=32. grid 768: b=bid&7, mt=(bid>>3)&31, ct=bid>>8.
// 4 waves: wave (wr=w&1, wc=w>>1) owns 32 rows x 64 cols. Per K-step:
// 12 global_load_lds(16B) ; barrier ; 6x ds_read_b128 + 10 MFMA.
// 12 KB LDS -> 3 blocks/CU (12 waves), balanced 768 = 3*256.
__global__ __launch_bounds__(256, 3) void k_pv(const unsigned short* __restrict__ Pbf,
                                               const unsigned short* __restrict__ xTbf,
                                               float* __restrict__ out){
  __shared__ unsigned short Al[64*32];     // 4 KB
  __shared__ unsigned short Bl[128*32];    // 8 KB
  int tid = threadIdx.x;
  int w = tid>>6, l = tid&63, q = l>>4, li = l&15;
  int b  = blockIdx.x & 7;
  int mt = (blockIdx.x>>3) & 31;
  int ct = blockIdx.x >> 8;                // 0..2
  int m0 = mt*64;
  int d0 = ct*128;
  const unsigned short* Pb  = Pbf  + (size_t)b*NN*NN;
  const unsigned short* xTb = xTbf + (size_t)b*ND*NN;

  int wr = w & 1, wc = w >> 1;

  // staging assignment: instr id = w*3+j ; id<4 -> A chunk id ; else B chunk id-4
  int lr = l>>2, lk = (l&3)*8;             // lane -> row-in-chunk, k-elems
  const unsigned short* gsrc0; const unsigned short* gsrc1; const unsigned short* gsrc2;
  unsigned short* ldst0; unsigned short* ldst1; unsigned short* ldst2;
  {
    int id0 = w*3, id1 = w*3+1, id2 = w*3+2;
    ldst0 = (id0<4 ? Al + id0*512 : Bl + (id0-4)*512);
    ldst1 = (id1<4 ? Al + id1*512 : Bl + (id1-4)*512);
    ldst2 = (id2<4 ? Al + id2*512 : Bl + (id2-4)*512);
    gsrc0 = (id0<4 ? Pb + (size_t)(m0 + id0*16 + lr)*NN + lk
                   : xTb + (size_t)(d0 + (id0-4)*16 + lr)*NN + lk);
    gsrc1 = (id1<4 ? Pb + (size_t)(m0 + id1*16 + lr)*NN + lk
                   : xTb + (size_t)(d0 + (id1-4)*16 + lr)*NN + lk);
    gsrc2 = (id2<4 ? Pb + (size_t)(m0 + id2*16 + lr)*NN + lk
                   : xTb + (size_t)(d0 + (id2-4)*16 + lr)*NN + lk);
  }

  f32x4 acc[2][4];
  #pragma unroll
  for(int nc=0;nc<2;nc++)
    #pragma unroll
    for(int t=0;t<4;t++) acc[nc][t] = (f32x4)(0.f);
  f32x4 rs[2] = {(f32x4)(0.f),(f32x4)(0.f)};
  bf16x8 ones;
  #pragma unroll
  for(int i=0;i<8;i++) ones[i] = (short)0x3F80;   // bf16 1.0

  for(int k0=0; k0<NN; k0+=32){
    __syncthreads();                       // previous compute done (LDS reuse)
    gl2lds16(gsrc0 + k0, ldst0);
    gl2lds16(gsrc1 + k0, ldst1);
    gl2lds16(gsrc2 + k0, ldst2);
    __syncthreads();                       // staging visible (vmcnt drain)
    bf16x8 a0 = *(const bf16x8*)&Al[(wr*32 +      li)*32 + q*8];
    bf16x8 a1 = *(const bf16x8*)&Al[(wr*32 + 16 + li)*32 + q*8];
    bf16x8 bv[4];
    #pragma unroll
    for(int t=0;t<4;t++)
      bv[t] = *(const bf16x8*)&Bl[(wc*64 + t*16 + li)*32 + q*8];
    #pragma unroll
    for(int t=0;t<4;t++){
      acc[0][t] = __builtin_amdgcn_mfma_f32_16x16x32_bf16(a0, bv[t], acc[0][t], 0,0,0);
      acc[1][t] = __builtin_amdgcn_mfma_f32_16x16x32_bf16(a1, bv[t], acc[1][t], 0,0,0);
    }
    rs[0] = __builtin_amdgcn_mfma_f32_16x16x32_bf16(a0, ones, rs[0], 0,0,0);
    rs[1] = __builtin_amdgcn_mfma_f32_16x16x32_bf16(a1, ones, rs[1], 0,0,0);
  }

  #pragma unroll
  for(int nc=0;nc<2;nc++)
    #pragma unroll
    for(int r=0;r<4;r++){
      int row = m0 + wr*32 + nc*16 + q*4 + r;
      float inv = 1.f/(rs[nc][r] + 1e-8f);
      float* orow = out + ((size_t)(b*NN + row))*ND + d0 + wc*64;
      #pragma unroll
      for(int t=0;t<4;t++)
        orow[t*16 + li] = acc[nc][t][r] * inv;
    }
}

// ---- segout; block 0 also reduces the loss partials ----
__global__ void k_segout(const int* __restrict__ seg, float* __restrict__ o,
                         const float* __restrict__ klp, const float* __restrict__ mp,
                         float* __restrict__ outLoss){
  int tid = threadIdx.x;
  int i = blockIdx.x*256 + tid;
  o[i] = (float)seg[i];
  if(blockIdx.x==0){
    __shared__ float sa[4], sm[4];
    float a=0.f, m=0.f;
    for(int k=tid; k<NBLK_LOSS; k+=256){ a += klp[k]; m += mp[k]; }
    a = wsum(a); m = wsum(m);
    if((tid&63)==0){ sa[tid>>6]=a; sm[tid>>6]=m; }
    __syncthreads();
    if(tid==0)
      outLoss[0] = (sa[0]+sa[1]+sa[2]+sa[3])/((sm[0]+sm[1]+sm[2]+sm[3])+1e-8f);
  }
}

extern "C" void kernel_launch(void* const* d_in, const int* in_sizes, int n_in,
                              void* d_out, int out_size, void* d_ws, size_t ws_size,
                              hipStream_t stream) {
  const float* x      = (const float*)d_in[0];
  const int*   seg    = (const int*)d_in[1];
  const float* protos = (const float*)d_in[2];

  float* out     = (float*)d_out;                  // (B,N,D)
  float* outSeg  = out + OUT_ELEMS;                // (B,H,W)
  float* outLoss = outSeg + SEG_ELEMS;             // scalar
  float* outC    = outLoss + 1;                    // (B,N,R)

  // ws layout (~83 MB)
  unsigned short* xTbf = (unsigned short*)d_ws;            // 8*384*2048 bf16 (12.6MB)
  unsigned short* Kbf  = xTbf + (size_t)NB*ND*NN;          // 8*2048*64 bf16 (2MB)
  unsigned short* Pbf  = Kbf + (size_t)NB*NN*NR;           // 8*2048*2048 bf16 (64MB)
  float* kn      = (float*)(Pbf + (size_t)NB*NN*NN);       // 24576 f32
  float* maskp   = kn + NR*ND;                             // 16384  -- zero region (64KB)
  unsigned* prox = (unsigned*)(maskp + NB*NN);             // 8*2048*64 u32 (4MB, fully written by k_seg)
  float* part    = (float*)(prox + (size_t)NB*NN*64);      // 8*32*64 (fully written)
  float* klp     = part + NB*32*64;                        // 4096 (fully written)
  float* mp      = klp + NBLK_LOSS;                        // 4096 (fully written)

  // only maskp needs zeroing (prox is fully written by k_seg)
  hipMemsetAsync(maskp, 0, (size_t)NB*NN*4, stream);

  k_proto <<<dim3(NR),           dim3(64),   0, stream>>>(protos, kn);
  k_seg   <<<dim3(256),          dim3(1024), 0, stream>>>(seg, maskp, prox);
  k_csim  <<<dim3(NB*NN/64),     dim3(256),  0, stream>>>(x, kn, outC, xTbf, part);
  k_lossfc<<<dim3(NBLK_LOSS),    dim3(256),  0, stream>>>(outC, part, maskp, klp, mp, Kbf);
  k_qk    <<<dim3(8192),         dim3(256),  0, stream>>>(Kbf, prox, Pbf);
  k_pv    <<<dim3(768),          dim3(256),  0, stream>>>(Pbf, xTbf, out);
  k_segout<<<dim3(SEG_ELEMS/256),dim3(256),  0, stream>>>(seg, outSeg, klp, mp, outLoss);
}